// Round 17
// baseline (222.077 us; speedup 1.0000x reference)
//
#include <hip/hip_runtime.h>
#include <hip/hip_bf16.h>
#include <stdint.h>

#define B_ 2
#define N_ 2048
#define DIM_ 1024
#define HEADS_ 16
#define DH_ 64
#define EPS_ 1e-5f

typedef __attribute__((ext_vector_type(4))) float f32x4;
typedef __attribute__((ext_vector_type(8))) float f32x8;
typedef __attribute__((ext_vector_type(16))) float f32x16;
typedef __attribute__((ext_vector_type(8))) __bf16 bf16x8;
typedef __attribute__((ext_vector_type(4))) unsigned int u32x4;
typedef __attribute__((ext_vector_type(2))) unsigned int u32x2;

__device__ __forceinline__ f32x4 mfma16(bf16x8 a, bf16x8 b, f32x4 c) {
  return __builtin_amdgcn_mfma_f32_16x16x32_bf16(a, b, c, 0, 0, 0);
}

__device__ __forceinline__ f32x16 mfma32(bf16x8 a, bf16x8 b, f32x16 c) {
  return __builtin_amdgcn_mfma_f32_32x32x16_bf16(a, b, c, 0, 0, 0);
}

__device__ __forceinline__ unsigned short f2bf(float x) {
  unsigned int u = __builtin_bit_cast(unsigned int, x);
  u += 0x7fffu + ((u >> 16) & 1u);
  return (unsigned short)(u >> 16);
}

__device__ __forceinline__ unsigned int cvt_pk_bf16(float lo, float hi) {
  unsigned int r;
  asm("v_cvt_pk_bf16_f32 %0, %1, %2" : "=v"(r) : "v"(lo), "v"(hi));
  return r;
}

__device__ __forceinline__ float uasf(unsigned int u) { return __builtin_bit_cast(float, u); }
__device__ __forceinline__ unsigned int fasu(float f) { return __builtin_bit_cast(unsigned int, f); }

__device__ __forceinline__ bf16x8 ld_frag(const unsigned short* p) {
  u32x4 v = *reinterpret_cast<const u32x4*>(p);
  return __builtin_bit_cast(bf16x8, v);
}

__device__ __forceinline__ void gload_lds16(const unsigned short* g, unsigned short* l) {
  __builtin_amdgcn_global_load_lds((const __attribute__((address_space(1))) void*)g,
                                   (__attribute__((address_space(3))) void*)l, 16, 0, 0);
}

// ---------------- LayerNorm over sequence axis ----------------
__global__ __launch_bounds__(256) void ln_part(const float* __restrict__ x,
                                               float* __restrict__ ps,
                                               float* __restrict__ pss) {
  const int d = blockIdx.x * 256 + threadIdx.x;
  const int b = blockIdx.y >> 4, sp = blockIdx.y & 15;
  const float* xp = x + (size_t)(b * N_ + sp * 128) * DIM_ + d;
  float s = 0.f, ss = 0.f;
  for (int i = 0; i < 128; ++i) {
    float v = xp[(size_t)i * DIM_];
    s += v;
    ss += v * v;
  }
  int c = b * DIM_ + d;
  ps[sp * (B_ * DIM_) + c] = s;
  pss[sp * (B_ * DIM_) + c] = ss;
}

__global__ void ln_fin(const float* __restrict__ ps, const float* __restrict__ pss,
                       const float* __restrict__ g, float* __restrict__ meanA,
                       float* __restrict__ sclA) {
  int c = blockIdx.x * 256 + threadIdx.x;
  float s = 0.f, ss = 0.f;
#pragma unroll
  for (int sp = 0; sp < 16; ++sp) {
    s += ps[sp * (B_ * DIM_) + c];
    ss += pss[sp * (B_ * DIM_) + c];
  }
  float m = s * (1.f / N_);
  float v = ss * (1.f / N_) - m * m;
  meanA[c] = m;
  sclA[c] = rsqrtf(fmaxf(v, EPS_)) * g[c & (DIM_ - 1)];
}

__global__ __launch_bounds__(256) void ln_apply(const float* __restrict__ x,
                                                const float* __restrict__ meanA,
                                                const float* __restrict__ sclA,
                                                unsigned short* __restrict__ xn) {
  size_t t = (size_t)blockIdx.x * 256 + threadIdx.x;
  size_t base = t * 8;
  int d0 = (int)(base & (DIM_ - 1));
  int b = base >= (size_t)N_ * DIM_;
  int c = b * DIM_ + d0;
  const float4* xp = reinterpret_cast<const float4*>(x + base);
  const float4* mp = reinterpret_cast<const float4*>(meanA + c);
  const float4* sp = reinterpret_cast<const float4*>(sclA + c);
  float4 x0 = xp[0], x1 = xp[1];
  float4 m0 = mp[0], m1 = mp[1];
  float4 s0 = sp[0], s1 = sp[1];
  union {
    unsigned short u[8];
    u32x4 v;
  } o;
  o.u[0] = f2bf((x0.x - m0.x) * s0.x);
  o.u[1] = f2bf((x0.y - m0.y) * s0.y);
  o.u[2] = f2bf((x0.z - m0.z) * s0.z);
  o.u[3] = f2bf((x0.w - m0.w) * s0.w);
  o.u[4] = f2bf((x1.x - m1.x) * s1.x);
  o.u[5] = f2bf((x1.y - m1.y) * s1.y);
  o.u[6] = f2bf((x1.z - m1.z) * s1.z);
  o.u[7] = f2bf((x1.w - m1.w) * s1.w);
  *reinterpret_cast<u32x4*>(xn + base) = o.v;
}

// ---------------- fp32 -> bf16 weight cast (optional scale) ----------------
__global__ __launch_bounds__(256) void cast_bf16(const float* __restrict__ src,
                                                 unsigned short* __restrict__ dst, float scale) {
  size_t t = (size_t)blockIdx.x * 256 + threadIdx.x;
  size_t base = t * 8;
  const float4* sp = reinterpret_cast<const float4*>(src + base);
  float4 a = sp[0], b4 = sp[1];
  union {
    unsigned short u[8];
    u32x4 v;
  } o;
  o.u[0] = f2bf(a.x * scale);
  o.u[1] = f2bf(a.y * scale);
  o.u[2] = f2bf(a.z * scale);
  o.u[3] = f2bf(a.w * scale);
  o.u[4] = f2bf(b4.x * scale);
  o.u[5] = f2bf(b4.y * scale);
  o.u[6] = f2bf(b4.z * scale);
  o.u[7] = f2bf(b4.w * scale);
  *reinterpret_cast<u32x4*>(dst + base) = o.v;
}

// ---------------- GEMM: C[M,Nc] = A[M,K]bf16 * W[Nc,K]bf16^T ----------------
template <bool OUT_F32>
__global__ __launch_bounds__(256) void gemm_bt(const unsigned short* __restrict__ A,
                                               const unsigned short* __restrict__ W,
                                               void* __restrict__ Cout, int K, int ldc) {
  __shared__ unsigned short sA[128 * 64];
  __shared__ unsigned short sB[128 * 64];
  const int tid = threadIdx.x, lane = tid & 63, w = tid >> 6;
  const int wm = w >> 1, wn = w & 1;
  const int l15 = lane & 15, l4 = lane >> 4;
  const int m0 = blockIdx.y * 128, n0 = blockIdx.x * 128;
  f32x4 acc[4][4] = {};
  for (int kt = 0; kt < K; kt += 64) {
    __syncthreads();
#pragma unroll
    for (int p = 0; p < 4; ++p) {
      int flat = p * 256 + tid;
      int row = flat >> 3, c = flat & 7;
      int cs = c ^ (row & 7);
      gload_lds16(A + (size_t)(m0 + row) * K + kt + cs * 8, sA + (size_t)(p * 256 + w * 64) * 8);
      gload_lds16(W + (size_t)(n0 + row) * K + kt + cs * 8, sB + (size_t)(p * 256 + w * 64) * 8);
    }
    __syncthreads();
#pragma unroll
    for (int kk = 0; kk < 2; ++kk) {
      bf16x8 af[4], bfr[4];
#pragma unroll
      for (int i = 0; i < 4; ++i) {
        int rowA = wm * 64 + i * 16 + l15;
        af[i] = ld_frag(sA + rowA * 64 + (((kk * 4 + l4) ^ (rowA & 7)) * 8));
        int rowB = wn * 64 + i * 16 + l15;
        bfr[i] = ld_frag(sB + rowB * 64 + (((kk * 4 + l4) ^ (rowB & 7)) * 8));
      }
#pragma unroll
      for (int i = 0; i < 4; ++i)
#pragma unroll
        for (int j = 0; j < 4; ++j) acc[i][j] = mfma16(af[i], bfr[j], acc[i][j]);
    }
  }
#pragma unroll
  for (int i = 0; i < 4; ++i)
#pragma unroll
    for (int j = 0; j < 4; ++j)
#pragma unroll
      for (int r = 0; r < 4; ++r) {
        size_t off =
            (size_t)(m0 + wm * 64 + i * 16 + l4 * 4 + r) * ldc + (n0 + wn * 64 + j * 16 + l15);
        if (OUT_F32)
          ((float*)Cout)[off] = acc[i][j][r];
        else
          ((unsigned short*)Cout)[off] = f2bf(acc[i][j][r]);
      }
}

// ---------------- V transpose: qkv v-block -> Vt[b][h][dh][n] ----------------
__global__ __launch_bounds__(256) void transpose_v(const unsigned short* __restrict__ qkv,
                                                   unsigned short* __restrict__ Vt) {
  __shared__ unsigned short tt[64][65];
  const int tid = threadIdx.x;
  const int h = blockIdx.y >> 1, b = blockIdx.y & 1;
  const int n0 = blockIdx.x * 64;
  const unsigned short* src = qkv + (size_t)(b * N_ + n0) * 3072 + 2048 + h * 64;
#pragma unroll
  for (int i = 0; i < 16; ++i) {
    int idx = i * 256 + tid;
    int r = idx >> 6, c = idx & 63;
    tt[r][c] = src[(size_t)r * 3072 + c];
  }
  __syncthreads();
  unsigned short* dst = Vt + (size_t)(b * HEADS_ + h) * 64 * N_ + n0;
#pragma unroll
  for (int i = 0; i < 16; ++i) {
    int idx = i * 256 + tid;
    int dh = idx >> 6, nn = idx & 63;
    dst[(size_t)dh * N_ + nn] = tt[nn][dh];
  }
}

// ---------------- Flash attention: full-iter bias cover, counted vmcnt ------
// 4 waves x 32 q (128 q/block), grid 512, 1 block/CU (160 KB LDS).
// Bias slices WAVE-PRIVATE, double-buffered: 4 x 2 x 16 KB = 128 KB.
// Per iter j: STAGE_BIAS(j+1 -> other slot) at TOP, then vmcnt(16) drains
// exactly bias[j](16)+KV[j](8) while bias[j+1] rides through the barrier ->
// bias gets a FULL iteration of cover; steady state = max(compute, service)
// instead of compute + service. Queue invariant per wave at the vmcnt:
// [bias[j](16) oldest, KV[j](8), bias[j+1](16) newest] - pinned by
// sched_barrier(0) after every stage group (r14 lesson: pins are load-bearing
// for counted drains). All data-path macros verbatim from passing r16.
__global__ __launch_bounds__(256, 1) void flash_attn(const unsigned short* __restrict__ qkv,
                                                     const float* __restrict__ bias,
                                                     const unsigned short* __restrict__ Vt,
                                                     unsigned short* __restrict__ Oatt) {
  __shared__ unsigned short sK[128 * 64];   // 16 KB: K pair tile (row=key)
  __shared__ unsigned short sV[64 * 128];   // 16 KB: V^T pair (row=dh)
  __shared__ float sBias[4][2][32 * 128];   // 128 KB: per-wave dbuf slices

  const int tid = threadIdx.x, lane = tid & 63, w = tid >> 6;  // w 0..3
  const int l31 = lane & 31, hi = lane >> 5;
  const int id = blockIdx.x;
  const int bh = id & 31, iblk = id >> 5;  // id%8 ~ XCD: heads pinned
  const int h = bh & 15, b = bh >> 4;
  const int qwb = iblk * 128 + w * 32;

  const unsigned short* Kg = qkv + (size_t)b * N_ * 3072 + 1024 + h * 64;
  const unsigned short* VtB = Vt + (size_t)(b * HEADS_ + h) * 64 * N_;
  const float* bias_h = bias + (size_t)h * N_ * N_;

  // K staging: 4 instrs; flat chunk = q*256 + w*64 + lane; row = flat>>3
  const int kr = w * 8 + (lane >> 3);
  const int kcs = (lane & 7) ^ (kr & 7);
  const unsigned short* kSrc = Kg + (size_t)kr * 3072 + kcs * 8;
  unsigned short* kDst = sK + (size_t)(w * 64) * 8;
  // V staging: 4 instrs; row = flat>>4
  const int vr = w * 4 + (lane >> 4);
  const int vcs = (lane & 15) ^ (vr & 15);
  const unsigned short* vSrc = VtB + (size_t)vr * N_ + vcs * 8;
  unsigned short* vDst = sV + (size_t)(w * 64) * 8;

#define STAGE_KV(JN)                                                          \
  {                                                                           \
    _Pragma("unroll") for (int q = 0; q < 4; ++q)                             \
        gload_lds16(kSrc + ((size_t)(JN) + q * 32) * 3072, kDst + q * 2048);  \
    _Pragma("unroll") for (int q = 0; q < 4; ++q)                             \
        gload_lds16(vSrc + (size_t)(q * 16) * N_ + (JN), vDst + q * 2048);    \
  }

  // Bias staging: 16 instrs/wave into OWN slice; instr i covers rows 2i..2i+1
  // (32 chunks of 16B per 512B row); slot s of row r holds global chunk s^r.
  const int brr = lane >> 5, bsl = lane & 31;
#define STAGE_BIAS(SLOT, JN)                                                   \
  {                                                                            \
    unsigned short* d_ = reinterpret_cast<unsigned short*>(&sBias[w][SLOT][0]); \
    _Pragma("unroll") for (int i = 0; i < 16; ++i) {                           \
      int rl_ = 2 * i + brr;                                                   \
      const float* s_ =                                                        \
          bias_h + (size_t)(qwb + rl_) * N_ + (JN) + ((bsl ^ rl_) << 2);       \
      gload_lds16((const unsigned short*)s_, d_ + i * 512);                    \
    }                                                                          \
  }

// C-block from LDS bias: C[rr] = bias[q=l31][CB*4 + 8*(rr>>2)+4*hi+(rr&3)]
#define LDBIAS(DST, MYB, CB)                                                   \
  {                                                                            \
    const float* myB_ = (MYB) + (size_t)l31 * 128;                             \
    f32x4 t0 = *reinterpret_cast<const f32x4*>(myB_ + ((((CB) + 0 + hi) ^ l31) << 2)); \
    f32x4 t1 = *reinterpret_cast<const f32x4*>(myB_ + ((((CB) + 2 + hi) ^ l31) << 2)); \
    f32x4 t2 = *reinterpret_cast<const f32x4*>(myB_ + ((((CB) + 4 + hi) ^ l31) << 2)); \
    f32x4 t3 = *reinterpret_cast<const f32x4*>(myB_ + ((((CB) + 6 + hi) ^ l31) << 2)); \
    f32x8 u0_ = __builtin_shufflevector(t0, t1, 0, 1, 2, 3, 4, 5, 6, 7);       \
    f32x8 u1_ = __builtin_shufflevector(t2, t3, 0, 1, 2, 3, 4, 5, 6, 7);       \
    DST = __builtin_shufflevector(u0_, u1_, 0, 1, 2, 3, 4, 5, 6, 7, 8, 9, 10,  \
                                  11, 12, 13, 14, 15);                         \
  }

#define FRAGK(OUT, ROWB, CH)                                            \
  {                                                                     \
    int row_ = (ROWB) + l31;                                            \
    OUT = ld_frag(sK + row_ * 64 + (((CH) ^ (row_ & 7)) * 8));          \
  }
#define FRAGV(OUT, ROWB, CH)                                            \
  {                                                                     \
    int row_ = (ROWB) + l31;                                            \
    OUT = ld_frag(sV + row_ * 128 + (((CH) ^ (row_ & 15)) * 8));        \
  }

// pack one 32-key S block into two PV B-frags (verified r9/r10/r12/r16)
#define PACK2(S, PLO, PHI)                                                 \
  {                                                                        \
    unsigned int w0 = cvt_pk_bf16(S[0], S[1]), w1 = cvt_pk_bf16(S[2], S[3]);     \
    unsigned int w2 = cvt_pk_bf16(S[4], S[5]), w3 = cvt_pk_bf16(S[6], S[7]);     \
    unsigned int w4 = cvt_pk_bf16(S[8], S[9]), w5 = cvt_pk_bf16(S[10], S[11]);   \
    unsigned int w6 = cvt_pk_bf16(S[12], S[13]), w7 = cvt_pk_bf16(S[14], S[15]); \
    auto rA = __builtin_amdgcn_permlane32_swap(w0, w2, false, false);      \
    auto rB = __builtin_amdgcn_permlane32_swap(w1, w3, false, false);      \
    auto rC = __builtin_amdgcn_permlane32_swap(w4, w6, false, false);      \
    auto rD = __builtin_amdgcn_permlane32_swap(w5, w7, false, false);      \
    u32x4 pw;                                                              \
    pw[0] = rA[0]; pw[1] = rB[0]; pw[2] = rA[1]; pw[3] = rB[1];            \
    PLO = __builtin_bit_cast(bf16x8, pw);                                  \
    pw[0] = rC[0]; pw[1] = rD[0]; pw[2] = rC[1]; pw[3] = rD[1];            \
    PHI = __builtin_bit_cast(bf16x8, pw);                                  \
  }

  // Q B-frags: qfK covers d = K*16 + hi*8 .. +7 for q = qwb + l31
  bf16x8 qf0, qf1, qf2, qf3;
  {
    const unsigned short* Qg =
        qkv + (size_t)(b * N_ + qwb + l31) * 3072 + h * 64 + hi * 8;
    qf0 = ld_frag(Qg);
    qf1 = ld_frag(Qg + 16);
    qf2 = ld_frag(Qg + 32);
    qf3 = ld_frag(Qg + 48);
  }

  f32x16 o0 = {}, o1 = {};
  float m_run = -1e30f, l_run = 0.f;

  // prologue (pinned groups): bias[0] -> slot0, KV[0]
  STAGE_BIAS(0, 0)
  __builtin_amdgcn_sched_barrier(0);
  STAGE_KV(0)
  __builtin_amdgcn_sched_barrier(0);

  const int NP = N_ / 128;  // 16 pairs
  for (int j = 0; j < NP; ++j) {
    const int slot = j & 1;
    // top: stage bias[j+1] into the OTHER slot, then counted drain
    if (j + 1 < NP) {
      STAGE_BIAS(slot ^ 1, (size_t)(j + 1) * 128)
      __builtin_amdgcn_sched_barrier(0);  // bias[j+1] = the newest 16
      asm volatile("s_waitcnt vmcnt(16)" ::: "memory");
    } else {
      asm volatile("s_waitcnt vmcnt(0)" ::: "memory");
    }
    __builtin_amdgcn_s_barrier();

    // bias regs for pair j (C-operands for the 4 S blocks)
    f32x16 SA0, SA1, SB0, SB1;
    float* sBw = &sBias[w][slot][0];
    LDBIAS(SA0, sBw, 0)
    LDBIAS(SA1, sBw, 8)
    LDBIAS(SB0, sBw, 16)
    LDBIAS(SB1, sBw, 24)
    asm volatile("s_waitcnt lgkmcnt(0)" ::: "memory");
    __builtin_amdgcn_sched_barrier(0);

    // S^T = K Q^T + bias for both tiles of the pair
    __builtin_amdgcn_s_setprio(1);
    {
      bf16x8 kf;
      FRAGK(kf, 0, 0 + hi)  SA0 = mfma32(kf, qf0, SA0);
      FRAGK(kf, 0, 2 + hi)  SA0 = mfma32(kf, qf1, SA0);
      FRAGK(kf, 0, 4 + hi)  SA0 = mfma32(kf, qf2, SA0);
      FRAGK(kf, 0, 6 + hi)  SA0 = mfma32(kf, qf3, SA0);
      FRAGK(kf, 32, 0 + hi) SA1 = mfma32(kf, qf0, SA1);
      FRAGK(kf, 32, 2 + hi) SA1 = mfma32(kf, qf1, SA1);
      FRAGK(kf, 32, 4 + hi) SA1 = mfma32(kf, qf2, SA1);
      FRAGK(kf, 32, 6 + hi) SA1 = mfma32(kf, qf3, SA1);
      FRAGK(kf, 64, 0 + hi) SB0 = mfma32(kf, qf0, SB0);
      FRAGK(kf, 64, 2 + hi) SB0 = mfma32(kf, qf1, SB0);
      FRAGK(kf, 64, 4 + hi) SB0 = mfma32(kf, qf2, SB0);
      FRAGK(kf, 64, 6 + hi) SB0 = mfma32(kf, qf3, SB0);
      FRAGK(kf, 96, 0 + hi) SB1 = mfma32(kf, qf0, SB1);
      FRAGK(kf, 96, 2 + hi) SB1 = mfma32(kf, qf1, SB1);
      FRAGK(kf, 96, 4 + hi) SB1 = mfma32(kf, qf2, SB1);
      FRAGK(kf, 96, 6 + hi) SB1 = mfma32(kf, qf3, SB1);
    }
    __builtin_amdgcn_s_setprio(0);

    // merged online softmax over 128 keys (4 parallel chains)
    float c0 = SA0[0], c1 = SA1[0], c2 = SB0[0], c3 = SB1[0];
#pragma unroll
    for (int i = 1; i < 16; ++i) {
      c0 = fmaxf(c0, SA0[i]);
      c1 = fmaxf(c1, SA1[i]);
      c2 = fmaxf(c2, SB0[i]);
      c3 = fmaxf(c3, SB1[i]);
    }
    float mx = fmaxf(fmaxf(c0, c1), fmaxf(c2, c3));
    {
      auto pr_ = __builtin_amdgcn_permlane32_swap(fasu(mx), fasu(mx), false, false);
      mx = fmaxf(uasf(pr_[0]), uasf(pr_[1]));
    }
    float mn = fmaxf(m_run, mx);
    float alpha = __expf(m_run - mn);
#pragma unroll
    for (int i = 0; i < 16; ++i) {
      SA0[i] = __expf(SA0[i] - mn);
      SA1[i] = __expf(SA1[i] - mn);
      SB0[i] = __expf(SB0[i] - mn);
      SB1[i] = __expf(SB1[i] - mn);
    }
    float r0 = 0.f, r1 = 0.f, r2 = 0.f, r3 = 0.f;
#pragma unroll
    for (int i = 0; i < 16; ++i) {
      r0 += SA0[i];
      r1 += SA1[i];
      r2 += SB0[i];
      r3 += SB1[i];
    }
    float rs = (r0 + r1) + (r2 + r3);
    {
      auto pr_ = __builtin_amdgcn_permlane32_swap(fasu(rs), fasu(rs), false, false);
      rs = uasf(pr_[0]) + uasf(pr_[1]);
    }
    l_run = l_run * alpha + rs;
    m_run = mn;
#pragma unroll
    for (int i = 0; i < 16; ++i) {
      o0[i] *= alpha;
      o1[i] *= alpha;
    }

    // P -> PV B-frags in-register
    bf16x8 pA0, pA1, pA2, pA3, pB0, pB1, pB2, pB3;
    PACK2(SA0, pA0, pA1)
    PACK2(SA1, pA2, pA3)
    PACK2(SB0, pB0, pB1)
    PACK2(SB1, pB2, pB3)

    // O^T += V^T P^T over the 128-key pair
    __builtin_amdgcn_s_setprio(1);
    {
      bf16x8 vf;
      FRAGV(vf, 0, 0 + hi)   o0 = mfma32(vf, pA0, o0);
      FRAGV(vf, 0, 2 + hi)   o0 = mfma32(vf, pA1, o0);
      FRAGV(vf, 0, 4 + hi)   o0 = mfma32(vf, pA2, o0);
      FRAGV(vf, 0, 6 + hi)   o0 = mfma32(vf, pA3, o0);
      FRAGV(vf, 0, 8 + hi)   o0 = mfma32(vf, pB0, o0);
      FRAGV(vf, 0, 10 + hi)  o0 = mfma32(vf, pB1, o0);
      FRAGV(vf, 0, 12 + hi)  o0 = mfma32(vf, pB2, o0);
      FRAGV(vf, 0, 14 + hi)  o0 = mfma32(vf, pB3, o0);
      FRAGV(vf, 32, 0 + hi)  o1 = mfma32(vf, pA0, o1);
      FRAGV(vf, 32, 2 + hi)  o1 = mfma32(vf, pA1, o1);
      FRAGV(vf, 32, 4 + hi)  o1 = mfma32(vf, pA2, o1);
      FRAGV(vf, 32, 6 + hi)  o1 = mfma32(vf, pA3, o1);
      FRAGV(vf, 32, 8 + hi)  o1 = mfma32(vf, pB0, o1);
      FRAGV(vf, 32, 10 + hi) o1 = mfma32(vf, pB1, o1);
      FRAGV(vf, 32, 12 + hi) o1 = mfma32(vf, pB2, o1);
      FRAGV(vf, 32, 14 + hi) o1 = mfma32(vf, pB3, o1);
    }
    __builtin_amdgcn_s_setprio(0);

    // all waves done reading K/V pair j -> stage pair j+1
    asm volatile("s_waitcnt lgkmcnt(0)" ::: "memory");
    __builtin_amdgcn_s_barrier();
    if (j + 1 < NP) {
      STAGE_KV((size_t)(j + 1) * 128)
      __builtin_amdgcn_sched_barrier(0);  // KV[j+1] older than bias[j+2]
    }
  }
#undef STAGE_KV
#undef STAGE_BIAS
#undef LDBIAS
#undef FRAGK
#undef FRAGV
#undef PACK2

  // epilogue: O[q][d] = O^T / l
  float inv = 1.f / l_run;
  unsigned short* orow =
      Oatt + (size_t)(b * N_ + qwb + l31) * 1024 + h * 64 + hi * 4;
#pragma unroll
  for (int g = 0; g < 4; ++g) {
    u32x2 pk0;
    pk0[0] = cvt_pk_bf16(o0[g * 4 + 0] * inv, o0[g * 4 + 1] * inv);
    pk0[1] = cvt_pk_bf16(o0[g * 4 + 2] * inv, o0[g * 4 + 3] * inv);
    *reinterpret_cast<u32x2*>(orow + g * 8) = pk0;
    u32x2 pk1;
    pk1[0] = cvt_pk_bf16(o1[g * 4 + 0] * inv, o1[g * 4 + 1] * inv);
    pk1[1] = cvt_pk_bf16(o1[g * 4 + 2] * inv, o1[g * 4 + 3] * inv);
    *reinterpret_cast<u32x2*>(orow + 32 + g * 8) = pk1;
  }
}

extern "C" void kernel_launch(void* const* d_in, const int* in_sizes, int n_in, void* d_out,
                              int out_size, void* d_ws, size_t ws_size, hipStream_t stream) {
  const float* x = (const float*)d_in[0];
  const float* bias = (const float*)d_in[1];
  const float* g = (const float*)d_in[2];
  const float* wq = (const float*)d_in[3];
  const float* wkv = (const float*)d_in[4];
  const float* wout = (const float*)d_in[5];
  float* out = (float*)d_out;

  float* ps = (float*)d_ws;
  float* pss = ps + 16 * B_ * DIM_;
  float* meanA = pss + 16 * B_ * DIM_;
  float* sclA = meanA + B_ * DIM_;
  unsigned short* xn = (unsigned short*)(sclA + B_ * DIM_);
  unsigned short* Wqkv = xn + (size_t)4096 * 1024;
  unsigned short* WoutB = Wqkv + (size_t)3072 * 1024;
  unsigned short* qkvb = WoutB + (size_t)1024 * 1024;
  unsigned short* Vt = qkvb + (size_t)4096 * 3072;
  unsigned short* Oatt = xn;  // alias: xn dead after QKV GEMM

  ln_part<<<dim3(DIM_ / 256, B_ * 16), 256, 0, stream>>>(x, ps, pss);
  ln_fin<<<dim3((B_ * DIM_) / 256), 256, 0, stream>>>(ps, pss, g, meanA, sclA);
  ln_apply<<<dim3((B_ * N_ * DIM_) / 2048), 256, 0, stream>>>(x, meanA, sclA, xn);
  cast_bf16<<<dim3((DIM_ * DIM_) / 2048), 256, 0, stream>>>(wq, Wqkv, 0.125f);
  cast_bf16<<<dim3((2 * DIM_ * DIM_) / 2048), 256, 0, stream>>>(wkv, Wqkv + (size_t)DIM_ * DIM_,
                                                                1.0f);
  cast_bf16<<<dim3((DIM_ * DIM_) / 2048), 256, 0, stream>>>(wout, WoutB, 1.0f);
  gemm_bt<false><<<dim3(3072 / 128, 4096 / 128), 256, 0, stream>>>(xn, Wqkv, qkvb, DIM_, 3072);
  transpose_v<<<dim3(N_ / 64, B_ * HEADS_), 256, 0, stream>>>(qkvb, Vt);
  flash_attn<<<dim3(512), 256, 0, stream>>>(qkvb, bias, Vt, Oatt);
  gemm_bt<true><<<dim3(1024 / 128, 4096 / 128), 256, 0, stream>>>(Oatt, WoutB, out, DIM_, 1024);
}

// Round 18
// 176.751 us; speedup vs baseline: 1.2564x; 1.2564x over previous
//
#include <hip/hip_runtime.h>
#include <hip/hip_bf16.h>
#include <stdint.h>

#define B_ 2
#define N_ 2048
#define DIM_ 1024
#define HEADS_ 16
#define DH_ 64
#define EPS_ 1e-5f

typedef __attribute__((ext_vector_type(4))) float f32x4;
typedef __attribute__((ext_vector_type(8))) float f32x8;
typedef __attribute__((ext_vector_type(16))) float f32x16;
typedef __attribute__((ext_vector_type(8))) __bf16 bf16x8;
typedef __attribute__((ext_vector_type(4))) unsigned int u32x4;
typedef __attribute__((ext_vector_type(2))) unsigned int u32x2;

__device__ __forceinline__ f32x4 mfma16(bf16x8 a, bf16x8 b, f32x4 c) {
  return __builtin_amdgcn_mfma_f32_16x16x32_bf16(a, b, c, 0, 0, 0);
}

__device__ __forceinline__ f32x16 mfma32(bf16x8 a, bf16x8 b, f32x16 c) {
  return __builtin_amdgcn_mfma_f32_32x32x16_bf16(a, b, c, 0, 0, 0);
}

__device__ __forceinline__ unsigned short f2bf(float x) {
  unsigned int u = __builtin_bit_cast(unsigned int, x);
  u += 0x7fffu + ((u >> 16) & 1u);
  return (unsigned short)(u >> 16);
}

__device__ __forceinline__ unsigned int cvt_pk_bf16(float lo, float hi) {
  unsigned int r;
  asm("v_cvt_pk_bf16_f32 %0, %1, %2" : "=v"(r) : "v"(lo), "v"(hi));
  return r;
}

__device__ __forceinline__ float uasf(unsigned int u) { return __builtin_bit_cast(float, u); }
__device__ __forceinline__ unsigned int fasu(float f) { return __builtin_bit_cast(unsigned int, f); }

__device__ __forceinline__ bf16x8 ld_frag(const unsigned short* p) {
  u32x4 v = *reinterpret_cast<const u32x4*>(p);
  return __builtin_bit_cast(bf16x8, v);
}

__device__ __forceinline__ void gload_lds16(const unsigned short* g, unsigned short* l) {
  __builtin_amdgcn_global_load_lds((const __attribute__((address_space(1))) void*)g,
                                   (__attribute__((address_space(3))) void*)l, 16, 0, 0);
}

// ---------------- LayerNorm over sequence axis ----------------
__global__ __launch_bounds__(256) void ln_part(const float* __restrict__ x,
                                               float* __restrict__ ps,
                                               float* __restrict__ pss) {
  const int d = blockIdx.x * 256 + threadIdx.x;
  const int b = blockIdx.y >> 4, sp = blockIdx.y & 15;
  const float* xp = x + (size_t)(b * N_ + sp * 128) * DIM_ + d;
  float s = 0.f, ss = 0.f;
  for (int i = 0; i < 128; ++i) {
    float v = xp[(size_t)i * DIM_];
    s += v;
    ss += v * v;
  }
  int c = b * DIM_ + d;
  ps[sp * (B_ * DIM_) + c] = s;
  pss[sp * (B_ * DIM_) + c] = ss;
}

__global__ void ln_fin(const float* __restrict__ ps, const float* __restrict__ pss,
                       const float* __restrict__ g, float* __restrict__ meanA,
                       float* __restrict__ sclA) {
  int c = blockIdx.x * 256 + threadIdx.x;
  float s = 0.f, ss = 0.f;
#pragma unroll
  for (int sp = 0; sp < 16; ++sp) {
    s += ps[sp * (B_ * DIM_) + c];
    ss += pss[sp * (B_ * DIM_) + c];
  }
  float m = s * (1.f / N_);
  float v = ss * (1.f / N_) - m * m;
  meanA[c] = m;
  sclA[c] = rsqrtf(fmaxf(v, EPS_)) * g[c & (DIM_ - 1)];
}

__global__ __launch_bounds__(256) void ln_apply(const float* __restrict__ x,
                                                const float* __restrict__ meanA,
                                                const float* __restrict__ sclA,
                                                unsigned short* __restrict__ xn) {
  size_t t = (size_t)blockIdx.x * 256 + threadIdx.x;
  size_t base = t * 8;
  int d0 = (int)(base & (DIM_ - 1));
  int b = base >= (size_t)N_ * DIM_;
  int c = b * DIM_ + d0;
  const float4* xp = reinterpret_cast<const float4*>(x + base);
  const float4* mp = reinterpret_cast<const float4*>(meanA + c);
  const float4* sp = reinterpret_cast<const float4*>(sclA + c);
  float4 x0 = xp[0], x1 = xp[1];
  float4 m0 = mp[0], m1 = mp[1];
  float4 s0 = sp[0], s1 = sp[1];
  union {
    unsigned short u[8];
    u32x4 v;
  } o;
  o.u[0] = f2bf((x0.x - m0.x) * s0.x);
  o.u[1] = f2bf((x0.y - m0.y) * s0.y);
  o.u[2] = f2bf((x0.z - m0.z) * s0.z);
  o.u[3] = f2bf((x0.w - m0.w) * s0.w);
  o.u[4] = f2bf((x1.x - m1.x) * s1.x);
  o.u[5] = f2bf((x1.y - m1.y) * s1.y);
  o.u[6] = f2bf((x1.z - m1.z) * s1.z);
  o.u[7] = f2bf((x1.w - m1.w) * s1.w);
  *reinterpret_cast<u32x4*>(xn + base) = o.v;
}

// ---------------- fp32 -> bf16 weight cast (optional scale) ----------------
__global__ __launch_bounds__(256) void cast_bf16(const float* __restrict__ src,
                                                 unsigned short* __restrict__ dst, float scale) {
  size_t t = (size_t)blockIdx.x * 256 + threadIdx.x;
  size_t base = t * 8;
  const float4* sp = reinterpret_cast<const float4*>(src + base);
  float4 a = sp[0], b4 = sp[1];
  union {
    unsigned short u[8];
    u32x4 v;
  } o;
  o.u[0] = f2bf(a.x * scale);
  o.u[1] = f2bf(a.y * scale);
  o.u[2] = f2bf(a.z * scale);
  o.u[3] = f2bf(a.w * scale);
  o.u[4] = f2bf(b4.x * scale);
  o.u[5] = f2bf(b4.y * scale);
  o.u[6] = f2bf(b4.z * scale);
  o.u[7] = f2bf(b4.w * scale);
  *reinterpret_cast<u32x4*>(dst + base) = o.v;
}

// ---------------- GEMM (T3-min 2-phase): C = A * W^T ------------------------
// 128x128 tile, BK=64, double-buffered LDS; per K-step: STAGE(next) issued
// BEFORE compute(cur), ONE vmcnt(0)+barrier per step (T3 minimum recipe).
template <bool OUT_F32>
__global__ __launch_bounds__(256) void gemm_bt(const unsigned short* __restrict__ A,
                                               const unsigned short* __restrict__ W,
                                               void* __restrict__ Cout, int K, int ldc) {
  __shared__ unsigned short sA[2][128 * 64];
  __shared__ unsigned short sB[2][128 * 64];
  const int tid = threadIdx.x, lane = tid & 63, w = tid >> 6;
  const int wm = w >> 1, wn = w & 1;
  const int l15 = lane & 15, l4 = lane >> 4;
  const int m0 = blockIdx.y * 128, n0 = blockIdx.x * 128;
  f32x4 acc[4][4] = {};

#define GSTAGE(S, KT)                                                          \
  {                                                                            \
    _Pragma("unroll") for (int p = 0; p < 4; ++p) {                            \
      int flat = p * 256 + tid;                                                \
      int row = flat >> 3, c = flat & 7;                                       \
      int cs = c ^ (row & 7);                                                  \
      gload_lds16(A + (size_t)(m0 + row) * K + (KT) + cs * 8,                  \
                  sA[S] + (size_t)(p * 256 + w * 64) * 8);                     \
      gload_lds16(W + (size_t)(n0 + row) * K + (KT) + cs * 8,                  \
                  sB[S] + (size_t)(p * 256 + w * 64) * 8);                     \
    }                                                                          \
  }

  GSTAGE(0, 0)
  asm volatile("s_waitcnt vmcnt(0)" ::: "memory");
  __builtin_amdgcn_s_barrier();

  const int NKT = K / 64;
  for (int ki = 0; ki < NKT; ++ki) {
    const int cur = ki & 1;
    if (ki + 1 < NKT) GSTAGE(cur ^ 1, (ki + 1) * 64)
    const unsigned short* cA = sA[cur];
    const unsigned short* cB = sB[cur];
#pragma unroll
    for (int kk = 0; kk < 2; ++kk) {
      bf16x8 af[4], bfr[4];
#pragma unroll
      for (int i = 0; i < 4; ++i) {
        int rowA = wm * 64 + i * 16 + l15;
        af[i] = ld_frag(cA + rowA * 64 + (((kk * 4 + l4) ^ (rowA & 7)) * 8));
        int rowB = wn * 64 + i * 16 + l15;
        bfr[i] = ld_frag(cB + rowB * 64 + (((kk * 4 + l4) ^ (rowB & 7)) * 8));
      }
#pragma unroll
      for (int i = 0; i < 4; ++i)
#pragma unroll
        for (int j = 0; j < 4; ++j) acc[i][j] = mfma16(af[i], bfr[j], acc[i][j]);
    }
    // one drain+barrier per K-step: next-buffer staging complete, all waves
    // done reading cur (so iter ki+1 may overwrite it)
    asm volatile("s_waitcnt vmcnt(0)" ::: "memory");
    __builtin_amdgcn_s_barrier();
  }
#undef GSTAGE

#pragma unroll
  for (int i = 0; i < 4; ++i)
#pragma unroll
    for (int j = 0; j < 4; ++j)
#pragma unroll
      for (int r = 0; r < 4; ++r) {
        size_t off =
            (size_t)(m0 + wm * 64 + i * 16 + l4 * 4 + r) * ldc + (n0 + wn * 64 + j * 16 + l15);
        if (OUT_F32)
          ((float*)Cout)[off] = acc[i][j][r];
        else
          ((unsigned short*)Cout)[off] = f2bf(acc[i][j][r]);
      }
}

// ---------------- V transpose: qkv v-block -> Vt[b][h][dh][n] ----------------
__global__ __launch_bounds__(256) void transpose_v(const unsigned short* __restrict__ qkv,
                                                   unsigned short* __restrict__ Vt) {
  __shared__ unsigned short tt[64][65];
  const int tid = threadIdx.x;
  const int h = blockIdx.y >> 1, b = blockIdx.y & 1;
  const int n0 = blockIdx.x * 64;
  const unsigned short* src = qkv + (size_t)(b * N_ + n0) * 3072 + 2048 + h * 64;
#pragma unroll
  for (int i = 0; i < 16; ++i) {
    int idx = i * 256 + tid;
    int r = idx >> 6, c = idx & 63;
    tt[r][c] = src[(size_t)r * 3072 + c];
  }
  __syncthreads();
  unsigned short* dst = Vt + (size_t)(b * HEADS_ + h) * 64 * N_ + n0;
#pragma unroll
  for (int i = 0; i < 16; ++i) {
    int idx = i * 256 + tid;
    int dh = idx >> 6, nn = idx & 63;
    dst[(size_t)dh * N_ + nn] = tt[nn][dh];
  }
}

// ---------------- Flash attention: 8 waves, 160KB LDS, 128-key pairs --------
// r12 kernel verbatim (best passing configuration, flash ~110 us).
__global__ __launch_bounds__(512, 2) void flash_attn(const unsigned short* __restrict__ qkv,
                                                     const float* __restrict__ bias,
                                                     const unsigned short* __restrict__ Vt,
                                                     unsigned short* __restrict__ Oatt) {
  __shared__ unsigned short sK[128 * 64];   // 16 KB: pair of K tiles, row=key
  __shared__ unsigned short sV[64 * 128];   // 16 KB: V^T pair, row=d
  __shared__ float sBias[8][32 * 128];      // 128 KB: per-wave 32q x 128k slice

  const int tid = threadIdx.x, lane = tid & 63, w = tid >> 6;  // w in 0..7
  const int l31 = lane & 31, hi = lane >> 5;
  const int r = blockIdx.x;
  const int bh = r & 31, iblk = r >> 5;  // iblk 0..7
  const int h = bh & 15, b = bh >> 4;
  const int qbase = iblk * 256 + w * 32;

  const unsigned short* Kg = qkv + (size_t)b * N_ * 3072 + 1024 + h * 64;
  const unsigned short* VtB = Vt + (size_t)(b * HEADS_ + h) * 64 * N_;
  const float* bias_h = bias + (size_t)h * N_ * N_;

  // ---- K/V staging (cooperative, 2 gload16/thread each) ----
  const int kflat0 = tid, kflat1 = 512 + tid;
  const int krow0 = kflat0 >> 3, kc0 = (kflat0 & 7) ^ (krow0 & 7);
  const int krow1 = kflat1 >> 3, kc1 = (kflat1 & 7) ^ (krow1 & 7);
  const int vrow0 = kflat0 >> 4, vc0 = (kflat0 & 15) ^ (vrow0 & 15);
  const int vrow1 = kflat1 >> 4, vc1 = (kflat1 & 15) ^ (vrow1 & 15);
  unsigned short* sKb0 = sK + (size_t)(w * 64) * 8;
  unsigned short* sKb1 = sK + (size_t)(512 + w * 64) * 8;
  unsigned short* sVb0 = sV + (size_t)(w * 64) * 8;
  unsigned short* sVb1 = sV + (size_t)(512 + w * 64) * 8;

#define STAGE_KV(JN)                                                       \
  gload_lds16(Kg + (size_t)((JN) + krow0) * 3072 + kc0 * 8, sKb0);         \
  gload_lds16(Kg + (size_t)((JN) + krow1) * 3072 + kc1 * 8, sKb1);         \
  gload_lds16(VtB + (size_t)vrow0 * N_ + (JN) + vc0 * 8, sVb0);            \
  gload_lds16(VtB + (size_t)vrow1 * N_ + (JN) + vc1 * 8, sVb1);

  // ---- bias staging: wave-private 32q x 128k, slot s of row r holds ----
  // ---- global chunk s ^ r; dest linear = instr*1024B + lane*16B       ----
  float* sBw = sBias[w];
  unsigned short* sBw_us = reinterpret_cast<unsigned short*>(sBw);
  const int brr = lane >> 5, bsl = lane & 31;
  const float* bQ = bias_h + (size_t)qbase * N_;
#define SBI(i, JN)                                                            \
  gload_lds16((const unsigned short*)(bQ + (size_t)(2 * (i) + brr) * N_ +     \
                                      (JN) + ((bsl ^ (2 * (i) + brr)) << 2)), \
              sBw_us + (i) * 512);
#define STAGE_BIAS(JN)                                                     \
  SBI(0, JN) SBI(1, JN) SBI(2, JN) SBI(3, JN) SBI(4, JN) SBI(5, JN)        \
  SBI(6, JN) SBI(7, JN) SBI(8, JN) SBI(9, JN) SBI(10, JN) SBI(11, JN)      \
  SBI(12, JN) SBI(13, JN) SBI(14, JN) SBI(15, JN)

// C-block from LDS bias: C[rr] = bias[q=l31][CB*4 + 8*(rr>>2)+4*hi+(rr&3)]
#define LDBIAS(DST, CB)                                                        \
  {                                                                            \
    const float* myB_ = sBw + l31 * 128;                                       \
    f32x4 t0 = *reinterpret_cast<const f32x4*>(myB_ + ((((CB) + 0 + hi) ^ l31) << 2)); \
    f32x4 t1 = *reinterpret_cast<const f32x4*>(myB_ + ((((CB) + 2 + hi) ^ l31) << 2)); \
    f32x4 t2 = *reinterpret_cast<const f32x4*>(myB_ + ((((CB) + 4 + hi) ^ l31) << 2)); \
    f32x4 t3 = *reinterpret_cast<const f32x4*>(myB_ + ((((CB) + 6 + hi) ^ l31) << 2)); \
    f32x8 u0_ = __builtin_shufflevector(t0, t1, 0, 1, 2, 3, 4, 5, 6, 7);       \
    f32x8 u1_ = __builtin_shufflevector(t2, t3, 0, 1, 2, 3, 4, 5, 6, 7);       \
    DST = __builtin_shufflevector(u0_, u1_, 0, 1, 2, 3, 4, 5, 6, 7, 8, 9, 10,  \
                                  11, 12, 13, 14, 15);                         \
  }

#define FRAGK(OUT, ROWB, CH)                                              \
  {                                                                       \
    int row_ = (ROWB) + l31;                                              \
    OUT = ld_frag(sK + row_ * 64 + (((CH) ^ (row_ & 7)) * 8));            \
  }
#define FRAGV(OUT, ROWB, CH)                                              \
  {                                                                       \
    int row_ = (ROWB) + l31;                                              \
    OUT = ld_frag(sV + row_ * 128 + (((CH) ^ (row_ & 15)) * 8));          \
  }

// pack one 32-key S block into two PV B-frags (verified r9/r10/r12)
#define PACK2(S, PLO, PHI)                                                 \
  {                                                                        \
    unsigned int w0 = cvt_pk_bf16(S[0], S[1]), w1 = cvt_pk_bf16(S[2], S[3]);     \
    unsigned int w2 = cvt_pk_bf16(S[4], S[5]), w3 = cvt_pk_bf16(S[6], S[7]);     \
    unsigned int w4 = cvt_pk_bf16(S[8], S[9]), w5 = cvt_pk_bf16(S[10], S[11]);   \
    unsigned int w6 = cvt_pk_bf16(S[12], S[13]), w7 = cvt_pk_bf16(S[14], S[15]); \
    auto rA = __builtin_amdgcn_permlane32_swap(w0, w2, false, false);      \
    auto rB = __builtin_amdgcn_permlane32_swap(w1, w3, false, false);      \
    auto rC = __builtin_amdgcn_permlane32_swap(w4, w6, false, false);      \
    auto rD = __builtin_amdgcn_permlane32_swap(w5, w7, false, false);      \
    u32x4 pw;                                                              \
    pw[0] = rA[0]; pw[1] = rB[0]; pw[2] = rA[1]; pw[3] = rB[1];            \
    PLO = __builtin_bit_cast(bf16x8, pw);                                  \
    pw[0] = rC[0]; pw[1] = rD[0]; pw[2] = rC[1]; pw[3] = rD[1];            \
    PHI = __builtin_bit_cast(bf16x8, pw);                                  \
  }

  // Q B-frags: qfK covers d = K*16 + hi*8 .. +7 for q = qbase + l31
  bf16x8 qf0, qf1, qf2, qf3;
  {
    const unsigned short* Qg =
        qkv + (size_t)(b * N_ + qbase + l31) * 3072 + h * 64 + hi * 8;
    qf0 = ld_frag(Qg);
    qf1 = ld_frag(Qg + 16);
    qf2 = ld_frag(Qg + 32);
    qf3 = ld_frag(Qg + 48);
  }

  f32x16 o0 = {}, o1 = {};
  float m_run = -1e30f, l_run = 0.f;

  // prologue: stage pair 0 (drained at loop-top vmcnt(0))
  STAGE_KV(0)
  STAGE_BIAS(0)

  const int NP = N_ / 128;  // 16 pairs
  for (int p = 0; p < NP; ++p) {
    asm volatile("s_waitcnt vmcnt(0) lgkmcnt(0)" ::: "memory");
    __builtin_amdgcn_s_barrier();

    // 1. bias regs for pair p (C-operands for the 4 S blocks)
    f32x16 SA0, SA1, SB0, SB1;
    LDBIAS(SA0, 0)
    LDBIAS(SA1, 8)
    LDBIAS(SB0, 16)
    LDBIAS(SB1, 24)
    asm volatile("s_waitcnt lgkmcnt(0)" ::: "memory");
    __builtin_amdgcn_sched_barrier(0);  // bias regs live before overwrite

    // 2. bias prefetch for pair p+1 (full-pair cover; wave-private slice)
    if (p + 1 < NP) {
      const size_t jn = (size_t)(p + 1) * 128;
      STAGE_BIAS(jn)
    }

    // 3. S^T = K Q^T + bias for both tiles of the pair
    __builtin_amdgcn_s_setprio(1);
    {
      bf16x8 kf;
      FRAGK(kf, 0, 0 + hi)  SA0 = mfma32(kf, qf0, SA0);
      FRAGK(kf, 0, 2 + hi)  SA0 = mfma32(kf, qf1, SA0);
      FRAGK(kf, 0, 4 + hi)  SA0 = mfma32(kf, qf2, SA0);
      FRAGK(kf, 0, 6 + hi)  SA0 = mfma32(kf, qf3, SA0);
      FRAGK(kf, 32, 0 + hi) SA1 = mfma32(kf, qf0, SA1);
      FRAGK(kf, 32, 2 + hi) SA1 = mfma32(kf, qf1, SA1);
      FRAGK(kf, 32, 4 + hi) SA1 = mfma32(kf, qf2, SA1);
      FRAGK(kf, 32, 6 + hi) SA1 = mfma32(kf, qf3, SA1);
      FRAGK(kf, 64, 0 + hi) SB0 = mfma32(kf, qf0, SB0);
      FRAGK(kf, 64, 2 + hi) SB0 = mfma32(kf, qf1, SB0);
      FRAGK(kf, 64, 4 + hi) SB0 = mfma32(kf, qf2, SB0);
      FRAGK(kf, 64, 6 + hi) SB0 = mfma32(kf, qf3, SB0);
      FRAGK(kf, 96, 0 + hi) SB1 = mfma32(kf, qf0, SB1);
      FRAGK(kf, 96, 2 + hi) SB1 = mfma32(kf, qf1, SB1);
      FRAGK(kf, 96, 4 + hi) SB1 = mfma32(kf, qf2, SB1);
      FRAGK(kf, 96, 6 + hi) SB1 = mfma32(kf, qf3, SB1);
    }
    __builtin_amdgcn_s_setprio(0);

    // 4. merged online softmax over 128 keys (4 parallel 15-deep chains)
    float c0 = SA0[0], c1 = SA1[0], c2 = SB0[0], c3 = SB1[0];
#pragma unroll
    for (int i = 1; i < 16; ++i) {
      c0 = fmaxf(c0, SA0[i]);
      c1 = fmaxf(c1, SA1[i]);
      c2 = fmaxf(c2, SB0[i]);
      c3 = fmaxf(c3, SB1[i]);
    }
    float mx = fmaxf(fmaxf(c0, c1), fmaxf(c2, c3));
    {
      auto pr_ = __builtin_amdgcn_permlane32_swap(fasu(mx), fasu(mx), false, false);
      mx = fmaxf(uasf(pr_[0]), uasf(pr_[1]));
    }
    float mn = fmaxf(m_run, mx);
    float alpha = __expf(m_run - mn);
#pragma unroll
    for (int i = 0; i < 16; ++i) {
      SA0[i] = __expf(SA0[i] - mn);
      SA1[i] = __expf(SA1[i] - mn);
      SB0[i] = __expf(SB0[i] - mn);
      SB1[i] = __expf(SB1[i] - mn);
    }
    float r0 = 0.f, r1 = 0.f, r2 = 0.f, r3 = 0.f;
#pragma unroll
    for (int i = 0; i < 16; ++i) {
      r0 += SA0[i];
      r1 += SA1[i];
      r2 += SB0[i];
      r3 += SB1[i];
    }
    float rs = (r0 + r1) + (r2 + r3);
    {
      auto pr_ = __builtin_amdgcn_permlane32_swap(fasu(rs), fasu(rs), false, false);
      rs = uasf(pr_[0]) + uasf(pr_[1]);
    }
    l_run = l_run * alpha + rs;
    m_run = mn;
#pragma unroll
    for (int i = 0; i < 16; ++i) {
      o0[i] *= alpha;
      o1[i] *= alpha;
    }

    // 5. P -> PV B-frags in-register
    bf16x8 pA0, pA1, pA2, pA3, pB0, pB1, pB2, pB3;
    PACK2(SA0, pA0, pA1)
    PACK2(SA1, pA2, pA3)
    PACK2(SB0, pB0, pB1)
    PACK2(SB1, pB2, pB3)

    // 6. O^T += V^T P^T over the 128-key pair
    __builtin_amdgcn_s_setprio(1);
    {
      bf16x8 vf;
      FRAGV(vf, 0, 0 + hi)   o0 = mfma32(vf, pA0, o0);
      FRAGV(vf, 0, 2 + hi)   o0 = mfma32(vf, pA1, o0);
      FRAGV(vf, 0, 4 + hi)   o0 = mfma32(vf, pA2, o0);
      FRAGV(vf, 0, 6 + hi)   o0 = mfma32(vf, pA3, o0);
      FRAGV(vf, 0, 8 + hi)   o0 = mfma32(vf, pB0, o0);
      FRAGV(vf, 0, 10 + hi)  o0 = mfma32(vf, pB1, o0);
      FRAGV(vf, 0, 12 + hi)  o0 = mfma32(vf, pB2, o0);
      FRAGV(vf, 0, 14 + hi)  o0 = mfma32(vf, pB3, o0);
      FRAGV(vf, 32, 0 + hi)  o1 = mfma32(vf, pA0, o1);
      FRAGV(vf, 32, 2 + hi)  o1 = mfma32(vf, pA1, o1);
      FRAGV(vf, 32, 4 + hi)  o1 = mfma32(vf, pA2, o1);
      FRAGV(vf, 32, 6 + hi)  o1 = mfma32(vf, pA3, o1);
      FRAGV(vf, 32, 8 + hi)  o1 = mfma32(vf, pB0, o1);
      FRAGV(vf, 32, 10 + hi) o1 = mfma32(vf, pB1, o1);
      FRAGV(vf, 32, 12 + hi) o1 = mfma32(vf, pB2, o1);
      FRAGV(vf, 32, 14 + hi) o1 = mfma32(vf, pB3, o1);
    }
    __builtin_amdgcn_s_setprio(0);

    // 7. all waves done reading K/V pair p -> stage pair p+1
    asm volatile("s_waitcnt lgkmcnt(0)" ::: "memory");
    __builtin_amdgcn_s_barrier();
    if (p + 1 < NP) {
      const size_t jn = (size_t)(p + 1) * 128;
      STAGE_KV(jn)
    }
  }
#undef STAGE_KV
#undef SBI
#undef STAGE_BIAS
#undef LDBIAS
#undef FRAGK
#undef FRAGV
#undef PACK2

  // epilogue: O[q][d] = O^T / l
  float inv = 1.f / l_run;
  unsigned short* orow =
      Oatt + (size_t)(b * N_ + qbase + l31) * 1024 + h * 64 + hi * 4;
#pragma unroll
  for (int g = 0; g < 4; ++g) {
    u32x2 pk0;
    pk0[0] = cvt_pk_bf16(o0[g * 4 + 0] * inv, o0[g * 4 + 1] * inv);
    pk0[1] = cvt_pk_bf16(o0[g * 4 + 2] * inv, o0[g * 4 + 3] * inv);
    *reinterpret_cast<u32x2*>(orow + g * 8) = pk0;
    u32x2 pk1;
    pk1[0] = cvt_pk_bf16(o1[g * 4 + 0] * inv, o1[g * 4 + 1] * inv);
    pk1[1] = cvt_pk_bf16(o1[g * 4 + 2] * inv, o1[g * 4 + 3] * inv);
    *reinterpret_cast<u32x2*>(orow + 32 + g * 8) = pk1;
  }
}

extern "C" void kernel_launch(void* const* d_in, const int* in_sizes, int n_in, void* d_out,
                              int out_size, void* d_ws, size_t ws_size, hipStream_t stream) {
  const float* x = (const float*)d_in[0];
  const float* bias = (const float*)d_in[1];
  const float* g = (const float*)d_in[2];
  const float* wq = (const float*)d_in[3];
  const float* wkv = (const float*)d_in[4];
  const float* wout = (const float*)d_in[5];
  float* out = (float*)d_out;

  float* ps = (float*)d_ws;
  float* pss = ps + 16 * B_ * DIM_;
  float* meanA = pss + 16 * B_ * DIM_;
  float* sclA = meanA + B_ * DIM_;
  unsigned short* xn = (unsigned short*)(sclA + B_ * DIM_);
  unsigned short* Wqkv = xn + (size_t)4096 * 1024;
  unsigned short* WoutB = Wqkv + (size_t)3072 * 1024;
  unsigned short* qkvb = WoutB + (size_t)1024 * 1024;
  unsigned short* Vt = qkvb + (size_t)4096 * 3072;
  unsigned short* Oatt = xn;  // alias: xn dead after QKV GEMM

  ln_part<<<dim3(DIM_ / 256, B_ * 16), 256, 0, stream>>>(x, ps, pss);
  ln_fin<<<dim3((B_ * DIM_) / 256), 256, 0, stream>>>(ps, pss, g, meanA, sclA);
  ln_apply<<<dim3((B_ * N_ * DIM_) / 2048), 256, 0, stream>>>(x, meanA, sclA, xn);
  cast_bf16<<<dim3((DIM_ * DIM_) / 2048), 256, 0, stream>>>(wq, Wqkv, 0.125f);
  cast_bf16<<<dim3((2 * DIM_ * DIM_) / 2048), 256, 0, stream>>>(wkv, Wqkv + (size_t)DIM_ * DIM_,
                                                                1.0f);
  cast_bf16<<<dim3((DIM_ * DIM_) / 2048), 256, 0, stream>>>(wout, WoutB, 1.0f);
  gemm_bt<false><<<dim3(3072 / 128, 4096 / 128), 256, 0, stream>>>(xn, Wqkv, qkvb, DIM_, 3072);
  transpose_v<<<dim3(N_ / 64, B_ * HEADS_), 256, 0, stream>>>(qkvb, Vt);
  flash_attn<<<dim3(256), 512, 0, stream>>>(qkvb, bias, Vt, Oatt);
  gemm_bt<true><<<dim3(1024 / 128, 4096 / 128), 256, 0, stream>>>(Oatt, WoutB, out, DIM_, 1024);
}

// Round 19
// 169.371 us; speedup vs baseline: 1.3112x; 1.0436x over previous
//
#include <hip/hip_runtime.h>
#include <hip/hip_bf16.h>
#include <stdint.h>

#define B_ 2
#define N_ 2048
#define DIM_ 1024
#define HEADS_ 16
#define DH_ 64
#define EPS_ 1e-5f

typedef __attribute__((ext_vector_type(4))) float f32x4;
typedef __attribute__((ext_vector_type(8))) float f32x8;
typedef __attribute__((ext_vector_type(16))) float f32x16;
typedef __attribute__((ext_vector_type(8))) __bf16 bf16x8;
typedef __attribute__((ext_vector_type(4))) unsigned int u32x4;
typedef __attribute__((ext_vector_type(2))) unsigned int u32x2;

__device__ __forceinline__ f32x4 mfma16(bf16x8 a, bf16x8 b, f32x4 c) {
  return __builtin_amdgcn_mfma_f32_16x16x32_bf16(a, b, c, 0, 0, 0);
}

__device__ __forceinline__ f32x16 mfma32(bf16x8 a, bf16x8 b, f32x16 c) {
  return __builtin_amdgcn_mfma_f32_32x32x16_bf16(a, b, c, 0, 0, 0);
}

__device__ __forceinline__ unsigned short f2bf(float x) {
  unsigned int u = __builtin_bit_cast(unsigned int, x);
  u += 0x7fffu + ((u >> 16) & 1u);
  return (unsigned short)(u >> 16);
}

__device__ __forceinline__ unsigned int cvt_pk_bf16(float lo, float hi) {
  unsigned int r;
  asm("v_cvt_pk_bf16_f32 %0, %1, %2" : "=v"(r) : "v"(lo), "v"(hi));
  return r;
}

__device__ __forceinline__ float uasf(unsigned int u) { return __builtin_bit_cast(float, u); }
__device__ __forceinline__ unsigned int fasu(float f) { return __builtin_bit_cast(unsigned int, f); }

__device__ __forceinline__ bf16x8 ld_frag(const unsigned short* p) {
  u32x4 v = *reinterpret_cast<const u32x4*>(p);
  return __builtin_bit_cast(bf16x8, v);
}

__device__ __forceinline__ void gload_lds16(const unsigned short* g, unsigned short* l) {
  __builtin_amdgcn_global_load_lds((const __attribute__((address_space(1))) void*)g,
                                   (__attribute__((address_space(3))) void*)l, 16, 0, 0);
}

// ---------------- LayerNorm over sequence axis ----------------
__global__ __launch_bounds__(256) void ln_part(const float* __restrict__ x,
                                               float* __restrict__ ps,
                                               float* __restrict__ pss) {
  const int d = blockIdx.x * 256 + threadIdx.x;
  const int b = blockIdx.y >> 4, sp = blockIdx.y & 15;
  const float* xp = x + (size_t)(b * N_ + sp * 128) * DIM_ + d;
  float s = 0.f, ss = 0.f;
  for (int i = 0; i < 128; ++i) {
    float v = xp[(size_t)i * DIM_];
    s += v;
    ss += v * v;
  }
  int c = b * DIM_ + d;
  ps[sp * (B_ * DIM_) + c] = s;
  pss[sp * (B_ * DIM_) + c] = ss;
}

__global__ void ln_fin(const float* __restrict__ ps, const float* __restrict__ pss,
                       const float* __restrict__ g, float* __restrict__ meanA,
                       float* __restrict__ sclA) {
  int c = blockIdx.x * 256 + threadIdx.x;
  float s = 0.f, ss = 0.f;
#pragma unroll
  for (int sp = 0; sp < 16; ++sp) {
    s += ps[sp * (B_ * DIM_) + c];
    ss += pss[sp * (B_ * DIM_) + c];
  }
  float m = s * (1.f / N_);
  float v = ss * (1.f / N_) - m * m;
  meanA[c] = m;
  sclA[c] = rsqrtf(fmaxf(v, EPS_)) * g[c & (DIM_ - 1)];
}

__global__ __launch_bounds__(256) void ln_apply(const float* __restrict__ x,
                                                const float* __restrict__ meanA,
                                                const float* __restrict__ sclA,
                                                unsigned short* __restrict__ xn) {
  size_t t = (size_t)blockIdx.x * 256 + threadIdx.x;
  size_t base = t * 8;
  int d0 = (int)(base & (DIM_ - 1));
  int b = base >= (size_t)N_ * DIM_;
  int c = b * DIM_ + d0;
  const float4* xp = reinterpret_cast<const float4*>(x + base);
  const float4* mp = reinterpret_cast<const float4*>(meanA + c);
  const float4* sp = reinterpret_cast<const float4*>(sclA + c);
  float4 x0 = xp[0], x1 = xp[1];
  float4 m0 = mp[0], m1 = mp[1];
  float4 s0 = sp[0], s1 = sp[1];
  union {
    unsigned short u[8];
    u32x4 v;
  } o;
  o.u[0] = f2bf((x0.x - m0.x) * s0.x);
  o.u[1] = f2bf((x0.y - m0.y) * s0.y);
  o.u[2] = f2bf((x0.z - m0.z) * s0.z);
  o.u[3] = f2bf((x0.w - m0.w) * s0.w);
  o.u[4] = f2bf((x1.x - m1.x) * s1.x);
  o.u[5] = f2bf((x1.y - m1.y) * s1.y);
  o.u[6] = f2bf((x1.z - m1.z) * s1.z);
  o.u[7] = f2bf((x1.w - m1.w) * s1.w);
  *reinterpret_cast<u32x4*>(xn + base) = o.v;
}

// ---------------- fp32 -> bf16 weight cast, all three weights in one --------
// Region layout (8-elem units per thread, 2048 blocks x 256 thr):
//   blocks [0,512):    wq   (1M elems)  scale 0.125 -> Wqkv[0..)
//   blocks [512,1536): wkv  (2M elems)  scale 1     -> Wqkv[1M..)
//   blocks [1536,2048): wout (1M elems) scale 1     -> WoutB
__global__ __launch_bounds__(256) void cast_all(const float* __restrict__ wq,
                                                const float* __restrict__ wkv,
                                                const float* __restrict__ wout,
                                                unsigned short* __restrict__ Wqkv,
                                                unsigned short* __restrict__ WoutB) {
  const int blk = blockIdx.x;
  const float* src;
  unsigned short* dst;
  float scale;
  size_t base;
  if (blk < 512) {
    base = ((size_t)blk * 256 + threadIdx.x) * 8;
    src = wq;
    dst = Wqkv;
    scale = 0.125f;
  } else if (blk < 1536) {
    base = ((size_t)(blk - 512) * 256 + threadIdx.x) * 8;
    src = wkv;
    dst = Wqkv + (size_t)DIM_ * DIM_;
    scale = 1.0f;
  } else {
    base = ((size_t)(blk - 1536) * 256 + threadIdx.x) * 8;
    src = wout;
    dst = WoutB;
    scale = 1.0f;
  }
  const float4* sp = reinterpret_cast<const float4*>(src + base);
  float4 a = sp[0], b4 = sp[1];
  union {
    unsigned short u[8];
    u32x4 v;
  } o;
  o.u[0] = f2bf(a.x * scale);
  o.u[1] = f2bf(a.y * scale);
  o.u[2] = f2bf(a.z * scale);
  o.u[3] = f2bf(a.w * scale);
  o.u[4] = f2bf(b4.x * scale);
  o.u[5] = f2bf(b4.y * scale);
  o.u[6] = f2bf(b4.z * scale);
  o.u[7] = f2bf(b4.w * scale);
  *reinterpret_cast<u32x4*>(dst + base) = o.v;
}

// ---------------- GEMM: C[M,Nc] = A[M,K]bf16 * W[Nc,K]bf16^T ----------------
// r12-proven single-buffer 128x128 tile, BK=64, 4 waves (2x2).
template <bool OUT_F32>
__global__ __launch_bounds__(256) void gemm_bt(const unsigned short* __restrict__ A,
                                               const unsigned short* __restrict__ W,
                                               void* __restrict__ Cout, int K, int ldc) {
  __shared__ unsigned short sA[128 * 64];
  __shared__ unsigned short sB[128 * 64];
  const int tid = threadIdx.x, lane = tid & 63, w = tid >> 6;
  const int wm = w >> 1, wn = w & 1;
  const int l15 = lane & 15, l4 = lane >> 4;
  const int m0 = blockIdx.y * 128, n0 = blockIdx.x * 128;
  f32x4 acc[4][4] = {};
  for (int kt = 0; kt < K; kt += 64) {
    __syncthreads();
#pragma unroll
    for (int p = 0; p < 4; ++p) {
      int flat = p * 256 + tid;
      int row = flat >> 3, c = flat & 7;
      int cs = c ^ (row & 7);
      gload_lds16(A + (size_t)(m0 + row) * K + kt + cs * 8, sA + (size_t)(p * 256 + w * 64) * 8);
      gload_lds16(W + (size_t)(n0 + row) * K + kt + cs * 8, sB + (size_t)(p * 256 + w * 64) * 8);
    }
    __syncthreads();
#pragma unroll
    for (int kk = 0; kk < 2; ++kk) {
      bf16x8 af[4], bfr[4];
#pragma unroll
      for (int i = 0; i < 4; ++i) {
        int rowA = wm * 64 + i * 16 + l15;
        af[i] = ld_frag(sA + rowA * 64 + (((kk * 4 + l4) ^ (rowA & 7)) * 8));
        int rowB = wn * 64 + i * 16 + l15;
        bfr[i] = ld_frag(sB + rowB * 64 + (((kk * 4 + l4) ^ (rowB & 7)) * 8));
      }
#pragma unroll
      for (int i = 0; i < 4; ++i)
#pragma unroll
        for (int j = 0; j < 4; ++j) acc[i][j] = mfma16(af[i], bfr[j], acc[i][j]);
    }
  }
#pragma unroll
  for (int i = 0; i < 4; ++i)
#pragma unroll
    for (int j = 0; j < 4; ++j)
#pragma unroll
      for (int r = 0; r < 4; ++r) {
        size_t off =
            (size_t)(m0 + wm * 64 + i * 16 + l4 * 4 + r) * ldc + (n0 + wn * 64 + j * 16 + l15);
        if (OUT_F32)
          ((float*)Cout)[off] = acc[i][j][r];
        else
          ((unsigned short*)Cout)[off] = f2bf(acc[i][j][r]);
      }
}

// ---------------- V transpose: qkv v-block -> Vt[b][h][dh][n] ----------------
__global__ __launch_bounds__(256) void transpose_v(const unsigned short* __restrict__ qkv,
                                                   unsigned short* __restrict__ Vt) {
  __shared__ unsigned short tt[64][65];
  const int tid = threadIdx.x;
  const int h = blockIdx.y >> 1, b = blockIdx.y & 1;
  const int n0 = blockIdx.x * 64;
  const unsigned short* src = qkv + (size_t)(b * N_ + n0) * 3072 + 2048 + h * 64;
#pragma unroll
  for (int i = 0; i < 16; ++i) {
    int idx = i * 256 + tid;
    int r = idx >> 6, c = idx & 63;
    tt[r][c] = src[(size_t)r * 3072 + c];
  }
  __syncthreads();
  unsigned short* dst = Vt + (size_t)(b * HEADS_ + h) * 64 * N_ + n0;
#pragma unroll
  for (int i = 0; i < 16; ++i) {
    int idx = i * 256 + tid;
    int dh = idx >> 6, nn = idx & 63;
    dst[(size_t)dh * N_ + nn] = tt[nn][dh];
  }
}

// ---------------- Flash attention: 8 waves, 160KB LDS, 128-key pairs --------
// r12 kernel verbatim (best passing configuration, flash ~110 us).
__global__ __launch_bounds__(512, 2) void flash_attn(const unsigned short* __restrict__ qkv,
                                                     const float* __restrict__ bias,
                                                     const unsigned short* __restrict__ Vt,
                                                     unsigned short* __restrict__ Oatt) {
  __shared__ unsigned short sK[128 * 64];   // 16 KB: pair of K tiles, row=key
  __shared__ unsigned short sV[64 * 128];   // 16 KB: V^T pair, row=d
  __shared__ float sBias[8][32 * 128];      // 128 KB: per-wave 32q x 128k slice

  const int tid = threadIdx.x, lane = tid & 63, w = tid >> 6;  // w in 0..7
  const int l31 = lane & 31, hi = lane >> 5;
  const int r = blockIdx.x;
  const int bh = r & 31, iblk = r >> 5;  // iblk 0..7
  const int h = bh & 15, b = bh >> 4;
  const int qbase = iblk * 256 + w * 32;

  const unsigned short* Kg = qkv + (size_t)b * N_ * 3072 + 1024 + h * 64;
  const unsigned short* VtB = Vt + (size_t)(b * HEADS_ + h) * 64 * N_;
  const float* bias_h = bias + (size_t)h * N_ * N_;

  // ---- K/V staging (cooperative, 2 gload16/thread each) ----
  const int kflat0 = tid, kflat1 = 512 + tid;
  const int krow0 = kflat0 >> 3, kc0 = (kflat0 & 7) ^ (krow0 & 7);
  const int krow1 = kflat1 >> 3, kc1 = (kflat1 & 7) ^ (krow1 & 7);
  const int vrow0 = kflat0 >> 4, vc0 = (kflat0 & 15) ^ (vrow0 & 15);
  const int vrow1 = kflat1 >> 4, vc1 = (kflat1 & 15) ^ (vrow1 & 15);
  unsigned short* sKb0 = sK + (size_t)(w * 64) * 8;
  unsigned short* sKb1 = sK + (size_t)(512 + w * 64) * 8;
  unsigned short* sVb0 = sV + (size_t)(w * 64) * 8;
  unsigned short* sVb1 = sV + (size_t)(512 + w * 64) * 8;

#define STAGE_KV(JN)                                                       \
  gload_lds16(Kg + (size_t)((JN) + krow0) * 3072 + kc0 * 8, sKb0);         \
  gload_lds16(Kg + (size_t)((JN) + krow1) * 3072 + kc1 * 8, sKb1);         \
  gload_lds16(VtB + (size_t)vrow0 * N_ + (JN) + vc0 * 8, sVb0);            \
  gload_lds16(VtB + (size_t)vrow1 * N_ + (JN) + vc1 * 8, sVb1);

  // ---- bias staging: wave-private 32q x 128k, slot s of row r holds ----
  // ---- global chunk s ^ r; dest linear = instr*1024B + lane*16B       ----
  float* sBw = sBias[w];
  unsigned short* sBw_us = reinterpret_cast<unsigned short*>(sBw);
  const int brr = lane >> 5, bsl = lane & 31;
  const float* bQ = bias_h + (size_t)qbase * N_;
#define SBI(i, JN)                                                            \
  gload_lds16((const unsigned short*)(bQ + (size_t)(2 * (i) + brr) * N_ +     \
                                      (JN) + ((bsl ^ (2 * (i) + brr)) << 2)), \
              sBw_us + (i) * 512);
#define STAGE_BIAS(JN)                                                     \
  SBI(0, JN) SBI(1, JN) SBI(2, JN) SBI(3, JN) SBI(4, JN) SBI(5, JN)        \
  SBI(6, JN) SBI(7, JN) SBI(8, JN) SBI(9, JN) SBI(10, JN) SBI(11, JN)      \
  SBI(12, JN) SBI(13, JN) SBI(14, JN) SBI(15, JN)

// C-block from LDS bias: C[rr] = bias[q=l31][CB*4 + 8*(rr>>2)+4*hi+(rr&3)]
#define LDBIAS(DST, CB)                                                        \
  {                                                                            \
    const float* myB_ = sBw + l31 * 128;                                       \
    f32x4 t0 = *reinterpret_cast<const f32x4*>(myB_ + ((((CB) + 0 + hi) ^ l31) << 2)); \
    f32x4 t1 = *reinterpret_cast<const f32x4*>(myB_ + ((((CB) + 2 + hi) ^ l31) << 2)); \
    f32x4 t2 = *reinterpret_cast<const f32x4*>(myB_ + ((((CB) + 4 + hi) ^ l31) << 2)); \
    f32x4 t3 = *reinterpret_cast<const f32x4*>(myB_ + ((((CB) + 6 + hi) ^ l31) << 2)); \
    f32x8 u0_ = __builtin_shufflevector(t0, t1, 0, 1, 2, 3, 4, 5, 6, 7);       \
    f32x8 u1_ = __builtin_shufflevector(t2, t3, 0, 1, 2, 3, 4, 5, 6, 7);       \
    DST = __builtin_shufflevector(u0_, u1_, 0, 1, 2, 3, 4, 5, 6, 7, 8, 9, 10,  \
                                  11, 12, 13, 14, 15);                         \
  }

#define FRAGK(OUT, ROWB, CH)                                              \
  {                                                                       \
    int row_ = (ROWB) + l31;                                              \
    OUT = ld_frag(sK + row_ * 64 + (((CH) ^ (row_ & 7)) * 8));            \
  }
#define FRAGV(OUT, ROWB, CH)                                              \
  {                                                                       \
    int row_ = (ROWB) + l31;                                              \
    OUT = ld_frag(sV + row_ * 128 + (((CH) ^ (row_ & 15)) * 8));          \
  }

// pack one 32-key S block into two PV B-frags (verified r9/r10/r12)
#define PACK2(S, PLO, PHI)                                                 \
  {                                                                        \
    unsigned int w0 = cvt_pk_bf16(S[0], S[1]), w1 = cvt_pk_bf16(S[2], S[3]);     \
    unsigned int w2 = cvt_pk_bf16(S[4], S[5]), w3 = cvt_pk_bf16(S[6], S[7]);     \
    unsigned int w4 = cvt_pk_bf16(S[8], S[9]), w5 = cvt_pk_bf16(S[10], S[11]);   \
    unsigned int w6 = cvt_pk_bf16(S[12], S[13]), w7 = cvt_pk_bf16(S[14], S[15]); \
    auto rA = __builtin_amdgcn_permlane32_swap(w0, w2, false, false);      \
    auto rB = __builtin_amdgcn_permlane32_swap(w1, w3, false, false);      \
    auto rC = __builtin_amdgcn_permlane32_swap(w4, w6, false, false);      \
    auto rD = __builtin_amdgcn_permlane32_swap(w5, w7, false, false);      \
    u32x4 pw;                                                              \
    pw[0] = rA[0]; pw[1] = rB[0]; pw[2] = rA[1]; pw[3] = rB[1];            \
    PLO = __builtin_bit_cast(bf16x8, pw);                                  \
    pw[0] = rC[0]; pw[1] = rD[0]; pw[2] = rC[1]; pw[3] = rD[1];            \
    PHI = __builtin_bit_cast(bf16x8, pw);                                  \
  }

  // Q B-frags: qfK covers d = K*16 + hi*8 .. +7 for q = qbase + l31
  bf16x8 qf0, qf1, qf2, qf3;
  {
    const unsigned short* Qg =
        qkv + (size_t)(b * N_ + qbase + l31) * 3072 + h * 64 + hi * 8;
    qf0 = ld_frag(Qg);
    qf1 = ld_frag(Qg + 16);
    qf2 = ld_frag(Qg + 32);
    qf3 = ld_frag(Qg + 48);
  }

  f32x16 o0 = {}, o1 = {};
  float m_run = -1e30f, l_run = 0.f;

  // prologue: stage pair 0 (drained at loop-top vmcnt(0))
  STAGE_KV(0)
  STAGE_BIAS(0)

  const int NP = N_ / 128;  // 16 pairs
  for (int p = 0; p < NP; ++p) {
    asm volatile("s_waitcnt vmcnt(0) lgkmcnt(0)" ::: "memory");
    __builtin_amdgcn_s_barrier();

    // 1. bias regs for pair p (C-operands for the 4 S blocks)
    f32x16 SA0, SA1, SB0, SB1;
    LDBIAS(SA0, 0)
    LDBIAS(SA1, 8)
    LDBIAS(SB0, 16)
    LDBIAS(SB1, 24)
    asm volatile("s_waitcnt lgkmcnt(0)" ::: "memory");
    __builtin_amdgcn_sched_barrier(0);  // bias regs live before overwrite

    // 2. bias prefetch for pair p+1 (full-pair cover; wave-private slice)
    if (p + 1 < NP) {
      const size_t jn = (size_t)(p + 1) * 128;
      STAGE_BIAS(jn)
    }

    // 3. S^T = K Q^T + bias for both tiles of the pair
    __builtin_amdgcn_s_setprio(1);
    {
      bf16x8 kf;
      FRAGK(kf, 0, 0 + hi)  SA0 = mfma32(kf, qf0, SA0);
      FRAGK(kf, 0, 2 + hi)  SA0 = mfma32(kf, qf1, SA0);
      FRAGK(kf, 0, 4 + hi)  SA0 = mfma32(kf, qf2, SA0);
      FRAGK(kf, 0, 6 + hi)  SA0 = mfma32(kf, qf3, SA0);
      FRAGK(kf, 32, 0 + hi) SA1 = mfma32(kf, qf0, SA1);
      FRAGK(kf, 32, 2 + hi) SA1 = mfma32(kf, qf1, SA1);
      FRAGK(kf, 32, 4 + hi) SA1 = mfma32(kf, qf2, SA1);
      FRAGK(kf, 32, 6 + hi) SA1 = mfma32(kf, qf3, SA1);
      FRAGK(kf, 64, 0 + hi) SB0 = mfma32(kf, qf0, SB0);
      FRAGK(kf, 64, 2 + hi) SB0 = mfma32(kf, qf1, SB0);
      FRAGK(kf, 64, 4 + hi) SB0 = mfma32(kf, qf2, SB0);
      FRAGK(kf, 64, 6 + hi) SB0 = mfma32(kf, qf3, SB0);
      FRAGK(kf, 96, 0 + hi) SB1 = mfma32(kf, qf0, SB1);
      FRAGK(kf, 96, 2 + hi) SB1 = mfma32(kf, qf1, SB1);
      FRAGK(kf, 96, 4 + hi) SB1 = mfma32(kf, qf2, SB1);
      FRAGK(kf, 96, 6 + hi) SB1 = mfma32(kf, qf3, SB1);
    }
    __builtin_amdgcn_s_setprio(0);

    // 4. merged online softmax over 128 keys (4 parallel 15-deep chains)
    float c0 = SA0[0], c1 = SA1[0], c2 = SB0[0], c3 = SB1[0];
#pragma unroll
    for (int i = 1; i < 16; ++i) {
      c0 = fmaxf(c0, SA0[i]);
      c1 = fmaxf(c1, SA1[i]);
      c2 = fmaxf(c2, SB0[i]);
      c3 = fmaxf(c3, SB1[i]);
    }
    float mx = fmaxf(fmaxf(c0, c1), fmaxf(c2, c3));
    {
      auto pr_ = __builtin_amdgcn_permlane32_swap(fasu(mx), fasu(mx), false, false);
      mx = fmaxf(uasf(pr_[0]), uasf(pr_[1]));
    }
    float mn = fmaxf(m_run, mx);
    float alpha = __expf(m_run - mn);
#pragma unroll
    for (int i = 0; i < 16; ++i) {
      SA0[i] = __expf(SA0[i] - mn);
      SA1[i] = __expf(SA1[i] - mn);
      SB0[i] = __expf(SB0[i] - mn);
      SB1[i] = __expf(SB1[i] - mn);
    }
    float r0 = 0.f, r1 = 0.f, r2 = 0.f, r3 = 0.f;
#pragma unroll
    for (int i = 0; i < 16; ++i) {
      r0 += SA0[i];
      r1 += SA1[i];
      r2 += SB0[i];
      r3 += SB1[i];
    }
    float rs = (r0 + r1) + (r2 + r3);
    {
      auto pr_ = __builtin_amdgcn_permlane32_swap(fasu(rs), fasu(rs), false, false);
      rs = uasf(pr_[0]) + uasf(pr_[1]);
    }
    l_run = l_run * alpha + rs;
    m_run = mn;
#pragma unroll
    for (int i = 0; i < 16; ++i) {
      o0[i] *= alpha;
      o1[i] *= alpha;
    }

    // 5. P -> PV B-frags in-register
    bf16x8 pA0, pA1, pA2, pA3, pB0, pB1, pB2, pB3;
    PACK2(SA0, pA0, pA1)
    PACK2(SA1, pA2, pA3)
    PACK2(SB0, pB0, pB1)
    PACK2(SB1, pB2, pB3)

    // 6. O^T += V^T P^T over the 128-key pair
    __builtin_amdgcn_s_setprio(1);
    {
      bf16x8 vf;
      FRAGV(vf, 0, 0 + hi)   o0 = mfma32(vf, pA0, o0);
      FRAGV(vf, 0, 2 + hi)   o0 = mfma32(vf, pA1, o0);
      FRAGV(vf, 0, 4 + hi)   o0 = mfma32(vf, pA2, o0);
      FRAGV(vf, 0, 6 + hi)   o0 = mfma32(vf, pA3, o0);
      FRAGV(vf, 0, 8 + hi)   o0 = mfma32(vf, pB0, o0);
      FRAGV(vf, 0, 10 + hi)  o0 = mfma32(vf, pB1, o0);
      FRAGV(vf, 0, 12 + hi)  o0 = mfma32(vf, pB2, o0);
      FRAGV(vf, 0, 14 + hi)  o0 = mfma32(vf, pB3, o0);
      FRAGV(vf, 32, 0 + hi)  o1 = mfma32(vf, pA0, o1);
      FRAGV(vf, 32, 2 + hi)  o1 = mfma32(vf, pA1, o1);
      FRAGV(vf, 32, 4 + hi)  o1 = mfma32(vf, pA2, o1);
      FRAGV(vf, 32, 6 + hi)  o1 = mfma32(vf, pA3, o1);
      FRAGV(vf, 32, 8 + hi)  o1 = mfma32(vf, pB0, o1);
      FRAGV(vf, 32, 10 + hi) o1 = mfma32(vf, pB1, o1);
      FRAGV(vf, 32, 12 + hi) o1 = mfma32(vf, pB2, o1);
      FRAGV(vf, 32, 14 + hi) o1 = mfma32(vf, pB3, o1);
    }
    __builtin_amdgcn_s_setprio(0);

    // 7. all waves done reading K/V pair p -> stage pair p+1
    asm volatile("s_waitcnt lgkmcnt(0)" ::: "memory");
    __builtin_amdgcn_s_barrier();
    if (p + 1 < NP) {
      const size_t jn = (size_t)(p + 1) * 128;
      STAGE_KV(jn)
    }
  }
#undef STAGE_KV
#undef SBI
#undef STAGE_BIAS
#undef LDBIAS
#undef FRAGK
#undef FRAGV
#undef PACK2

  // epilogue: O[q][d] = O^T / l
  float inv = 1.f / l_run;
  unsigned short* orow =
      Oatt + (size_t)(b * N_ + qbase + l31) * 1024 + h * 64 + hi * 4;
#pragma unroll
  for (int g = 0; g < 4; ++g) {
    u32x2 pk0;
    pk0[0] = cvt_pk_bf16(o0[g * 4 + 0] * inv, o0[g * 4 + 1] * inv);
    pk0[1] = cvt_pk_bf16(o0[g * 4 + 2] * inv, o0[g * 4 + 3] * inv);
    *reinterpret_cast<u32x2*>(orow + g * 8) = pk0;
    u32x2 pk1;
    pk1[0] = cvt_pk_bf16(o1[g * 4 + 0] * inv, o1[g * 4 + 1] * inv);
    pk1[1] = cvt_pk_bf16(o1[g * 4 + 2] * inv, o1[g * 4 + 3] * inv);
    *reinterpret_cast<u32x2*>(orow + 32 + g * 8) = pk1;
  }
}

extern "C" void kernel_launch(void* const* d_in, const int* in_sizes, int n_in, void* d_out,
                              int out_size, void* d_ws, size_t ws_size, hipStream_t stream) {
  const float* x = (const float*)d_in[0];
  const float* bias = (const float*)d_in[1];
  const float* g = (const float*)d_in[2];
  const float* wq = (const float*)d_in[3];
  const float* wkv = (const float*)d_in[4];
  const float* wout = (const float*)d_in[5];
  float* out = (float*)d_out;

  float* ps = (float*)d_ws;
  float* pss = ps + 16 * B_ * DIM_;
  float* meanA = pss + 16 * B_ * DIM_;
  float* sclA = meanA + B_ * DIM_;
  unsigned short* xn = (unsigned short*)(sclA + B_ * DIM_);
  unsigned short* Wqkv = xn + (size_t)4096 * 1024;
  unsigned short* WoutB = Wqkv + (size_t)3072 * 1024;
  unsigned short* qkvb = WoutB + (size_t)1024 * 1024;
  unsigned short* Vt = qkvb + (size_t)4096 * 3072;
  unsigned short* Oatt = xn;  // alias: xn dead after QKV GEMM

  ln_part<<<dim3(DIM_ / 256, B_ * 16), 256, 0, stream>>>(x, ps, pss);
  ln_fin<<<dim3((B_ * DIM_) / 256), 256, 0, stream>>>(ps, pss, g, meanA, sclA);
  ln_apply<<<dim3((B_ * N_ * DIM_) / 2048), 256, 0, stream>>>(x, meanA, sclA, xn);
  cast_all<<<dim3(2048), 256, 0, stream>>>(wq, wkv, wout, Wqkv, WoutB);
  gemm_bt<false><<<dim3(3072 / 128, 4096 / 128), 256, 0, stream>>>(xn, Wqkv, qkvb, DIM_, 3072);
  transpose_v<<<dim3(N_ / 64, B_ * HEADS_), 256, 0, stream>>>(qkvb, Vt);
  flash_attn<<<dim3(256), 512, 0, stream>>>(qkvb, bias, Vt, Oatt);
  gemm_bt<true><<<dim3(1024 / 128, 4096 / 128), 256, 0, stream>>>(Oatt, WoutB, out, DIM_, 1024);
}

// Round 20
// 168.457 us; speedup vs baseline: 1.3183x; 1.0054x over previous
//
#include <hip/hip_runtime.h>
#include <hip/hip_bf16.h>
#include <stdint.h>

#define B_ 2
#define N_ 2048
#define DIM_ 1024
#define HEADS_ 16
#define DH_ 64
#define EPS_ 1e-5f

typedef __attribute__((ext_vector_type(4))) float f32x4;
typedef __attribute__((ext_vector_type(8))) float f32x8;
typedef __attribute__((ext_vector_type(16))) float f32x16;
typedef __attribute__((ext_vector_type(8))) __bf16 bf16x8;
typedef __attribute__((ext_vector_type(4))) unsigned int u32x4;
typedef __attribute__((ext_vector_type(2))) unsigned int u32x2;

__device__ __forceinline__ f32x4 mfma16(bf16x8 a, bf16x8 b, f32x4 c) {
  return __builtin_amdgcn_mfma_f32_16x16x32_bf16(a, b, c, 0, 0, 0);
}

__device__ __forceinline__ f32x16 mfma32(bf16x8 a, bf16x8 b, f32x16 c) {
  return __builtin_amdgcn_mfma_f32_32x32x16_bf16(a, b, c, 0, 0, 0);
}

__device__ __forceinline__ unsigned short f2bf(float x) {
  unsigned int u = __builtin_bit_cast(unsigned int, x);
  u += 0x7fffu + ((u >> 16) & 1u);
  return (unsigned short)(u >> 16);
}

__device__ __forceinline__ unsigned int cvt_pk_bf16(float lo, float hi) {
  unsigned int r;
  asm("v_cvt_pk_bf16_f32 %0, %1, %2" : "=v"(r) : "v"(lo), "v"(hi));
  return r;
}

__device__ __forceinline__ float uasf(unsigned int u) { return __builtin_bit_cast(float, u); }
__device__ __forceinline__ unsigned int fasu(float f) { return __builtin_bit_cast(unsigned int, f); }

__device__ __forceinline__ bf16x8 ld_frag(const unsigned short* p) {
  u32x4 v = *reinterpret_cast<const u32x4*>(p);
  return __builtin_bit_cast(bf16x8, v);
}

__device__ __forceinline__ void gload_lds16(const unsigned short* g, unsigned short* l) {
  __builtin_amdgcn_global_load_lds((const __attribute__((address_space(1))) void*)g,
                                   (__attribute__((address_space(3))) void*)l, 16, 0, 0);
}

// ---------------- LayerNorm over sequence axis ----------------
__global__ __launch_bounds__(256) void ln_part(const float* __restrict__ x,
                                               float* __restrict__ ps,
                                               float* __restrict__ pss) {
  const int d = blockIdx.x * 256 + threadIdx.x;
  const int b = blockIdx.y >> 4, sp = blockIdx.y & 15;
  const float* xp = x + (size_t)(b * N_ + sp * 128) * DIM_ + d;
  float s = 0.f, ss = 0.f;
  for (int i = 0; i < 128; ++i) {
    float v = xp[(size_t)i * DIM_];
    s += v;
    ss += v * v;
  }
  int c = b * DIM_ + d;
  ps[sp * (B_ * DIM_) + c] = s;
  pss[sp * (B_ * DIM_) + c] = ss;
}

__global__ void ln_fin(const float* __restrict__ ps, const float* __restrict__ pss,
                       const float* __restrict__ g, float* __restrict__ meanA,
                       float* __restrict__ sclA) {
  int c = blockIdx.x * 256 + threadIdx.x;
  float s = 0.f, ss = 0.f;
#pragma unroll
  for (int sp = 0; sp < 16; ++sp) {
    s += ps[sp * (B_ * DIM_) + c];
    ss += pss[sp * (B_ * DIM_) + c];
  }
  float m = s * (1.f / N_);
  float v = ss * (1.f / N_) - m * m;
  meanA[c] = m;
  sclA[c] = rsqrtf(fmaxf(v, EPS_)) * g[c & (DIM_ - 1)];
}

__global__ __launch_bounds__(256) void ln_apply(const float* __restrict__ x,
                                                const float* __restrict__ meanA,
                                                const float* __restrict__ sclA,
                                                unsigned short* __restrict__ xn) {
  size_t t = (size_t)blockIdx.x * 256 + threadIdx.x;
  size_t base = t * 8;
  int d0 = (int)(base & (DIM_ - 1));
  int b = base >= (size_t)N_ * DIM_;
  int c = b * DIM_ + d0;
  const float4* xp = reinterpret_cast<const float4*>(x + base);
  const float4* mp = reinterpret_cast<const float4*>(meanA + c);
  const float4* sp = reinterpret_cast<const float4*>(sclA + c);
  float4 x0 = xp[0], x1 = xp[1];
  float4 m0 = mp[0], m1 = mp[1];
  float4 s0 = sp[0], s1 = sp[1];
  union {
    unsigned short u[8];
    u32x4 v;
  } o;
  o.u[0] = f2bf((x0.x - m0.x) * s0.x);
  o.u[1] = f2bf((x0.y - m0.y) * s0.y);
  o.u[2] = f2bf((x0.z - m0.z) * s0.z);
  o.u[3] = f2bf((x0.w - m0.w) * s0.w);
  o.u[4] = f2bf((x1.x - m1.x) * s1.x);
  o.u[5] = f2bf((x1.y - m1.y) * s1.y);
  o.u[6] = f2bf((x1.z - m1.z) * s1.z);
  o.u[7] = f2bf((x1.w - m1.w) * s1.w);
  *reinterpret_cast<u32x4*>(xn + base) = o.v;
}

// ---------------- fp32 -> bf16 weight cast, all three weights in one --------
__global__ __launch_bounds__(256) void cast_all(const float* __restrict__ wq,
                                                const float* __restrict__ wkv,
                                                const float* __restrict__ wout,
                                                unsigned short* __restrict__ Wqkv,
                                                unsigned short* __restrict__ WoutB) {
  const int blk = blockIdx.x;
  const float* src;
  unsigned short* dst;
  float scale;
  size_t base;
  if (blk < 512) {
    base = ((size_t)blk * 256 + threadIdx.x) * 8;
    src = wq;
    dst = Wqkv;
    scale = 0.125f;
  } else if (blk < 1536) {
    base = ((size_t)(blk - 512) * 256 + threadIdx.x) * 8;
    src = wkv;
    dst = Wqkv + (size_t)DIM_ * DIM_;
    scale = 1.0f;
  } else {
    base = ((size_t)(blk - 1536) * 256 + threadIdx.x) * 8;
    src = wout;
    dst = WoutB;
    scale = 1.0f;
  }
  const float4* sp = reinterpret_cast<const float4*>(src + base);
  float4 a = sp[0], b4 = sp[1];
  union {
    unsigned short u[8];
    u32x4 v;
  } o;
  o.u[0] = f2bf(a.x * scale);
  o.u[1] = f2bf(a.y * scale);
  o.u[2] = f2bf(a.z * scale);
  o.u[3] = f2bf(a.w * scale);
  o.u[4] = f2bf(b4.x * scale);
  o.u[5] = f2bf(b4.y * scale);
  o.u[6] = f2bf(b4.z * scale);
  o.u[7] = f2bf(b4.w * scale);
  *reinterpret_cast<u32x4*>(dst + base) = o.v;
}

// ---------------- GEMM: C[M,Nc] = A[M,K]bf16 * W[Nc,K]bf16^T ----------------
template <bool OUT_F32>
__global__ __launch_bounds__(256) void gemm_bt(const unsigned short* __restrict__ A,
                                               const unsigned short* __restrict__ W,
                                               void* __restrict__ Cout, int K, int ldc) {
  __shared__ unsigned short sA[128 * 64];
  __shared__ unsigned short sB[128 * 64];
  const int tid = threadIdx.x, lane = tid & 63, w = tid >> 6;
  const int wm = w >> 1, wn = w & 1;
  const int l15 = lane & 15, l4 = lane >> 4;
  const int m0 = blockIdx.y * 128, n0 = blockIdx.x * 128;
  f32x4 acc[4][4] = {};
  for (int kt = 0; kt < K; kt += 64) {
    __syncthreads();
#pragma unroll
    for (int p = 0; p < 4; ++p) {
      int flat = p * 256 + tid;
      int row = flat >> 3, c = flat & 7;
      int cs = c ^ (row & 7);
      gload_lds16(A + (size_t)(m0 + row) * K + kt + cs * 8, sA + (size_t)(p * 256 + w * 64) * 8);
      gload_lds16(W + (size_t)(n0 + row) * K + kt + cs * 8, sB + (size_t)(p * 256 + w * 64) * 8);
    }
    __syncthreads();
#pragma unroll
    for (int kk = 0; kk < 2; ++kk) {
      bf16x8 af[4], bfr[4];
#pragma unroll
      for (int i = 0; i < 4; ++i) {
        int rowA = wm * 64 + i * 16 + l15;
        af[i] = ld_frag(sA + rowA * 64 + (((kk * 4 + l4) ^ (rowA & 7)) * 8));
        int rowB = wn * 64 + i * 16 + l15;
        bfr[i] = ld_frag(sB + rowB * 64 + (((kk * 4 + l4) ^ (rowB & 7)) * 8));
      }
#pragma unroll
      for (int i = 0; i < 4; ++i)
#pragma unroll
        for (int j = 0; j < 4; ++j) acc[i][j] = mfma16(af[i], bfr[j], acc[i][j]);
    }
  }
#pragma unroll
  for (int i = 0; i < 4; ++i)
#pragma unroll
    for (int j = 0; j < 4; ++j)
#pragma unroll
      for (int r = 0; r < 4; ++r) {
        size_t off =
            (size_t)(m0 + wm * 64 + i * 16 + l4 * 4 + r) * ldc + (n0 + wn * 64 + j * 16 + l15);
        if (OUT_F32)
          ((float*)Cout)[off] = acc[i][j][r];
        else
          ((unsigned short*)Cout)[off] = f2bf(acc[i][j][r]);
      }
}

// ---------------- V transpose: qkv v-block -> Vt[b][h][dh][n] ----------------
__global__ __launch_bounds__(256) void transpose_v(const unsigned short* __restrict__ qkv,
                                                   unsigned short* __restrict__ Vt) {
  __shared__ unsigned short tt[64][65];
  const int tid = threadIdx.x;
  const int h = blockIdx.y >> 1, b = blockIdx.y & 1;
  const int n0 = blockIdx.x * 64;
  const unsigned short* src = qkv + (size_t)(b * N_ + n0) * 3072 + 2048 + h * 64;
#pragma unroll
  for (int i = 0; i < 16; ++i) {
    int idx = i * 256 + tid;
    int r = idx >> 6, c = idx & 63;
    tt[r][c] = src[(size_t)r * 3072 + c];
  }
  __syncthreads();
  unsigned short* dst = Vt + (size_t)(b * HEADS_ + h) * 64 * N_ + n0;
#pragma unroll
  for (int i = 0; i < 16; ++i) {
    int idx = i * 256 + tid;
    int dh = idx >> 6, nn = idx & 63;
    dst[(size_t)dh * N_ + nn] = tt[nn][dh];
  }
}

// ---------------- Flash attention: 8 waves, 160KB LDS, 128-key pairs --------
// r12/r19 structure + T13 defer-max (THR=8): skip the O-rescale when the
// tile max doesn't exceed the running max by more than 8 (wave-uniform
// branch via __all). P is then bounded by e^8, which fp32 l and bf16 P
// tolerate (softmax weights are scale-invariant). First pair never skips.
__global__ __launch_bounds__(512, 2) void flash_attn(const unsigned short* __restrict__ qkv,
                                                     const float* __restrict__ bias,
                                                     const unsigned short* __restrict__ Vt,
                                                     unsigned short* __restrict__ Oatt) {
  __shared__ unsigned short sK[128 * 64];   // 16 KB: pair of K tiles, row=key
  __shared__ unsigned short sV[64 * 128];   // 16 KB: V^T pair, row=d
  __shared__ float sBias[8][32 * 128];      // 128 KB: per-wave 32q x 128k slice

  const int tid = threadIdx.x, lane = tid & 63, w = tid >> 6;  // w in 0..7
  const int l31 = lane & 31, hi = lane >> 5;
  const int r = blockIdx.x;
  const int bh = r & 31, iblk = r >> 5;  // iblk 0..7
  const int h = bh & 15, b = bh >> 4;
  const int qbase = iblk * 256 + w * 32;

  const unsigned short* Kg = qkv + (size_t)b * N_ * 3072 + 1024 + h * 64;
  const unsigned short* VtB = Vt + (size_t)(b * HEADS_ + h) * 64 * N_;
  const float* bias_h = bias + (size_t)h * N_ * N_;

  // ---- K/V staging (cooperative, 2 gload16/thread each) ----
  const int kflat0 = tid, kflat1 = 512 + tid;
  const int krow0 = kflat0 >> 3, kc0 = (kflat0 & 7) ^ (krow0 & 7);
  const int krow1 = kflat1 >> 3, kc1 = (kflat1 & 7) ^ (krow1 & 7);
  const int vrow0 = kflat0 >> 4, vc0 = (kflat0 & 15) ^ (vrow0 & 15);
  const int vrow1 = kflat1 >> 4, vc1 = (kflat1 & 15) ^ (vrow1 & 15);
  unsigned short* sKb0 = sK + (size_t)(w * 64) * 8;
  unsigned short* sKb1 = sK + (size_t)(512 + w * 64) * 8;
  unsigned short* sVb0 = sV + (size_t)(w * 64) * 8;
  unsigned short* sVb1 = sV + (size_t)(512 + w * 64) * 8;

#define STAGE_KV(JN)                                                       \
  gload_lds16(Kg + (size_t)((JN) + krow0) * 3072 + kc0 * 8, sKb0);         \
  gload_lds16(Kg + (size_t)((JN) + krow1) * 3072 + kc1 * 8, sKb1);         \
  gload_lds16(VtB + (size_t)vrow0 * N_ + (JN) + vc0 * 8, sVb0);            \
  gload_lds16(VtB + (size_t)vrow1 * N_ + (JN) + vc1 * 8, sVb1);

  // ---- bias staging: wave-private 32q x 128k, slot s of row r holds ----
  // ---- global chunk s ^ r; dest linear = instr*1024B + lane*16B       ----
  float* sBw = sBias[w];
  unsigned short* sBw_us = reinterpret_cast<unsigned short*>(sBw);
  const int brr = lane >> 5, bsl = lane & 31;
  const float* bQ = bias_h + (size_t)qbase * N_;
#define SBI(i, JN)                                                            \
  gload_lds16((const unsigned short*)(bQ + (size_t)(2 * (i) + brr) * N_ +     \
                                      (JN) + ((bsl ^ (2 * (i) + brr)) << 2)), \
              sBw_us + (i) * 512);
#define STAGE_BIAS(JN)                                                     \
  SBI(0, JN) SBI(1, JN) SBI(2, JN) SBI(3, JN) SBI(4, JN) SBI(5, JN)        \
  SBI(6, JN) SBI(7, JN) SBI(8, JN) SBI(9, JN) SBI(10, JN) SBI(11, JN)      \
  SBI(12, JN) SBI(13, JN) SBI(14, JN) SBI(15, JN)

// C-block from LDS bias: C[rr] = bias[q=l31][CB*4 + 8*(rr>>2)+4*hi+(rr&3)]
#define LDBIAS(DST, CB)                                                        \
  {                                                                            \
    const float* myB_ = sBw + l31 * 128;                                       \
    f32x4 t0 = *reinterpret_cast<const f32x4*>(myB_ + ((((CB) + 0 + hi) ^ l31) << 2)); \
    f32x4 t1 = *reinterpret_cast<const f32x4*>(myB_ + ((((CB) + 2 + hi) ^ l31) << 2)); \
    f32x4 t2 = *reinterpret_cast<const f32x4*>(myB_ + ((((CB) + 4 + hi) ^ l31) << 2)); \
    f32x4 t3 = *reinterpret_cast<const f32x4*>(myB_ + ((((CB) + 6 + hi) ^ l31) << 2)); \
    f32x8 u0_ = __builtin_shufflevector(t0, t1, 0, 1, 2, 3, 4, 5, 6, 7);       \
    f32x8 u1_ = __builtin_shufflevector(t2, t3, 0, 1, 2, 3, 4, 5, 6, 7);       \
    DST = __builtin_shufflevector(u0_, u1_, 0, 1, 2, 3, 4, 5, 6, 7, 8, 9, 10,  \
                                  11, 12, 13, 14, 15);                         \
  }

#define FRAGK(OUT, ROWB, CH)                                              \
  {                                                                       \
    int row_ = (ROWB) + l31;                                              \
    OUT = ld_frag(sK + row_ * 64 + (((CH) ^ (row_ & 7)) * 8));            \
  }
#define FRAGV(OUT, ROWB, CH)                                              \
  {                                                                       \
    int row_ = (ROWB) + l31;                                              \
    OUT = ld_frag(sV + row_ * 128 + (((CH) ^ (row_ & 15)) * 8));          \
  }

// pack one 32-key S block into two PV B-frags (verified r9/r10/r12)
#define PACK2(S, PLO, PHI)                                                 \
  {                                                                        \
    unsigned int w0 = cvt_pk_bf16(S[0], S[1]), w1 = cvt_pk_bf16(S[2], S[3]);     \
    unsigned int w2 = cvt_pk_bf16(S[4], S[5]), w3 = cvt_pk_bf16(S[6], S[7]);     \
    unsigned int w4 = cvt_pk_bf16(S[8], S[9]), w5 = cvt_pk_bf16(S[10], S[11]);   \
    unsigned int w6 = cvt_pk_bf16(S[12], S[13]), w7 = cvt_pk_bf16(S[14], S[15]); \
    auto rA = __builtin_amdgcn_permlane32_swap(w0, w2, false, false);      \
    auto rB = __builtin_amdgcn_permlane32_swap(w1, w3, false, false);      \
    auto rC = __builtin_amdgcn_permlane32_swap(w4, w6, false, false);      \
    auto rD = __builtin_amdgcn_permlane32_swap(w5, w7, false, false);      \
    u32x4 pw;                                                              \
    pw[0] = rA[0]; pw[1] = rB[0]; pw[2] = rA[1]; pw[3] = rB[1];            \
    PLO = __builtin_bit_cast(bf16x8, pw);                                  \
    pw[0] = rC[0]; pw[1] = rD[0]; pw[2] = rC[1]; pw[3] = rD[1];            \
    PHI = __builtin_bit_cast(bf16x8, pw);                                  \
  }

  // Q B-frags: qfK covers d = K*16 + hi*8 .. +7 for q = qbase + l31
  bf16x8 qf0, qf1, qf2, qf3;
  {
    const unsigned short* Qg =
        qkv + (size_t)(b * N_ + qbase + l31) * 3072 + h * 64 + hi * 8;
    qf0 = ld_frag(Qg);
    qf1 = ld_frag(Qg + 16);
    qf2 = ld_frag(Qg + 32);
    qf3 = ld_frag(Qg + 48);
  }

  f32x16 o0 = {}, o1 = {};
  float m_run = -1e30f, l_run = 0.f;

  // prologue: stage pair 0 (drained at loop-top vmcnt(0))
  STAGE_KV(0)
  STAGE_BIAS(0)

  const int NP = N_ / 128;  // 16 pairs
  for (int p = 0; p < NP; ++p) {
    asm volatile("s_waitcnt vmcnt(0) lgkmcnt(0)" ::: "memory");
    __builtin_amdgcn_s_barrier();

    // 1. bias regs for pair p (C-operands for the 4 S blocks)
    f32x16 SA0, SA1, SB0, SB1;
    LDBIAS(SA0, 0)
    LDBIAS(SA1, 8)
    LDBIAS(SB0, 16)
    LDBIAS(SB1, 24)
    asm volatile("s_waitcnt lgkmcnt(0)" ::: "memory");
    __builtin_amdgcn_sched_barrier(0);  // bias regs live before overwrite

    // 2. bias prefetch for pair p+1 (full-pair cover; wave-private slice)
    if (p + 1 < NP) {
      const size_t jn = (size_t)(p + 1) * 128;
      STAGE_BIAS(jn)
    }

    // 3. S^T = K Q^T + bias for both tiles of the pair
    __builtin_amdgcn_s_setprio(1);
    {
      bf16x8 kf;
      FRAGK(kf, 0, 0 + hi)  SA0 = mfma32(kf, qf0, SA0);
      FRAGK(kf, 0, 2 + hi)  SA0 = mfma32(kf, qf1, SA0);
      FRAGK(kf, 0, 4 + hi)  SA0 = mfma32(kf, qf2, SA0);
      FRAGK(kf, 0, 6 + hi)  SA0 = mfma32(kf, qf3, SA0);
      FRAGK(kf, 32, 0 + hi) SA1 = mfma32(kf, qf0, SA1);
      FRAGK(kf, 32, 2 + hi) SA1 = mfma32(kf, qf1, SA1);
      FRAGK(kf, 32, 4 + hi) SA1 = mfma32(kf, qf2, SA1);
      FRAGK(kf, 32, 6 + hi) SA1 = mfma32(kf, qf3, SA1);
      FRAGK(kf, 64, 0 + hi) SB0 = mfma32(kf, qf0, SB0);
      FRAGK(kf, 64, 2 + hi) SB0 = mfma32(kf, qf1, SB0);
      FRAGK(kf, 64, 4 + hi) SB0 = mfma32(kf, qf2, SB0);
      FRAGK(kf, 64, 6 + hi) SB0 = mfma32(kf, qf3, SB0);
      FRAGK(kf, 96, 0 + hi) SB1 = mfma32(kf, qf0, SB1);
      FRAGK(kf, 96, 2 + hi) SB1 = mfma32(kf, qf1, SB1);
      FRAGK(kf, 96, 4 + hi) SB1 = mfma32(kf, qf2, SB1);
      FRAGK(kf, 96, 6 + hi) SB1 = mfma32(kf, qf3, SB1);
    }
    __builtin_amdgcn_s_setprio(0);

    // 4. merged online softmax over 128 keys, T13 defer-max (THR=8)
    float c0 = SA0[0], c1 = SA1[0], c2 = SB0[0], c3 = SB1[0];
#pragma unroll
    for (int i = 1; i < 16; ++i) {
      c0 = fmaxf(c0, SA0[i]);
      c1 = fmaxf(c1, SA1[i]);
      c2 = fmaxf(c2, SB0[i]);
      c3 = fmaxf(c3, SB1[i]);
    }
    float mx = fmaxf(fmaxf(c0, c1), fmaxf(c2, c3));
    {
      auto pr_ = __builtin_amdgcn_permlane32_swap(fasu(mx), fasu(mx), false, false);
      mx = fmaxf(uasf(pr_[0]), uasf(pr_[1]));
    }
    if (!__all(mx <= m_run + 8.f)) {
      // rescale path: new running max
      float mn = fmaxf(m_run, mx);
      float alpha = __expf(m_run - mn);
      l_run *= alpha;
#pragma unroll
      for (int i = 0; i < 16; ++i) {
        o0[i] *= alpha;
        o1[i] *= alpha;
      }
      m_run = mn;
    }
    // P = exp(S - m_run); bounded by e^8 in the deferred case
#pragma unroll
    for (int i = 0; i < 16; ++i) {
      SA0[i] = __expf(SA0[i] - m_run);
      SA1[i] = __expf(SA1[i] - m_run);
      SB0[i] = __expf(SB0[i] - m_run);
      SB1[i] = __expf(SB1[i] - m_run);
    }
    float r0 = 0.f, r1 = 0.f, r2 = 0.f, r3 = 0.f;
#pragma unroll
    for (int i = 0; i < 16; ++i) {
      r0 += SA0[i];
      r1 += SA1[i];
      r2 += SB0[i];
      r3 += SB1[i];
    }
    float rs = (r0 + r1) + (r2 + r3);
    {
      auto pr_ = __builtin_amdgcn_permlane32_swap(fasu(rs), fasu(rs), false, false);
      rs = uasf(pr_[0]) + uasf(pr_[1]);
    }
    l_run = l_run + rs;

    // 5. P -> PV B-frags in-register
    bf16x8 pA0, pA1, pA2, pA3, pB0, pB1, pB2, pB3;
    PACK2(SA0, pA0, pA1)
    PACK2(SA1, pA2, pA3)
    PACK2(SB0, pB0, pB1)
    PACK2(SB1, pB2, pB3)

    // 6. O^T += V^T P^T over the 128-key pair
    __builtin_amdgcn_s_setprio(1);
    {
      bf16x8 vf;
      FRAGV(vf, 0, 0 + hi)   o0 = mfma32(vf, pA0, o0);
      FRAGV(vf, 0, 2 + hi)   o0 = mfma32(vf, pA1, o0);
      FRAGV(vf, 0, 4 + hi)   o0 = mfma32(vf, pA2, o0);
      FRAGV(vf, 0, 6 + hi)   o0 = mfma32(vf, pA3, o0);
      FRAGV(vf, 0, 8 + hi)   o0 = mfma32(vf, pB0, o0);
      FRAGV(vf, 0, 10 + hi)  o0 = mfma32(vf, pB1, o0);
      FRAGV(vf, 0, 12 + hi)  o0 = mfma32(vf, pB2, o0);
      FRAGV(vf, 0, 14 + hi)  o0 = mfma32(vf, pB3, o0);
      FRAGV(vf, 32, 0 + hi)  o1 = mfma32(vf, pA0, o1);
      FRAGV(vf, 32, 2 + hi)  o1 = mfma32(vf, pA1, o1);
      FRAGV(vf, 32, 4 + hi)  o1 = mfma32(vf, pA2, o1);
      FRAGV(vf, 32, 6 + hi)  o1 = mfma32(vf, pA3, o1);
      FRAGV(vf, 32, 8 + hi)  o1 = mfma32(vf, pB0, o1);
      FRAGV(vf, 32, 10 + hi) o1 = mfma32(vf, pB1, o1);
      FRAGV(vf, 32, 12 + hi) o1 = mfma32(vf, pB2, o1);
      FRAGV(vf, 32, 14 + hi) o1 = mfma32(vf, pB3, o1);
    }
    __builtin_amdgcn_s_setprio(0);

    // 7. all waves done reading K/V pair p -> stage pair p+1
    asm volatile("s_waitcnt lgkmcnt(0)" ::: "memory");
    __builtin_amdgcn_s_barrier();
    if (p + 1 < NP) {
      const size_t jn = (size_t)(p + 1) * 128;
      STAGE_KV(jn)
    }
  }
#undef STAGE_KV
#undef SBI
#undef STAGE_BIAS
#undef LDBIAS
#undef FRAGK
#undef FRAGV
#undef PACK2

  // epilogue: O[q][d] = O^T / l
  float inv = 1.f / l_run;
  unsigned short* orow =
      Oatt + (size_t)(b * N_ + qbase + l31) * 1024 + h * 64 + hi * 4;
#pragma unroll
  for (int g = 0; g < 4; ++g) {
    u32x2 pk0;
    pk0[0] = cvt_pk_bf16(o0[g * 4 + 0] * inv, o0[g * 4 + 1] * inv);
    pk0[1] = cvt_pk_bf16(o0[g * 4 + 2] * inv, o0[g * 4 + 3] * inv);
    *reinterpret_cast<u32x2*>(orow + g * 8) = pk0;
    u32x2 pk1;
    pk1[0] = cvt_pk_bf16(o1[g * 4 + 0] * inv, o1[g * 4 + 1] * inv);
    pk1[1] = cvt_pk_bf16(o1[g * 4 + 2] * inv, o1[g * 4 + 3] * inv);
    *reinterpret_cast<u32x2*>(orow + 32 + g * 8) = pk1;
  }
}

extern "C" void kernel_launch(void* const* d_in, const int* in_sizes, int n_in, void* d_out,
                              int out_size, void* d_ws, size_t ws_size, hipStream_t stream) {
  const float* x = (const float*)d_in[0];
  const float* bias = (const float*)d_in[1];
  const float* g = (const float*)d_in[2];
  const float* wq = (const float*)d_in[3];
  const float* wkv = (const float*)d_in[4];
  const float* wout = (const float*)d_in[5];
  float* out = (float*)d_out;

  float* ps = (float*)d_ws;
  float* pss = ps + 16 * B_ * DIM_;
  float* meanA = pss + 16 * B_ * DIM_;
  float* sclA = meanA + B_ * DIM_;
  unsigned short* xn = (unsigned short*)(sclA + B_ * DIM_);
  unsigned short* Wqkv = xn + (size_t)4096 * 1024;
  unsigned short* WoutB = Wqkv + (size_t)3072 * 1024;
  unsigned short* qkvb = WoutB + (size_t)1024 * 1024;
  unsigned short* Vt = qkvb + (size_t)4096 * 3072;
  unsigned short* Oatt = xn;  // alias: xn dead after QKV GEMM

  ln_part<<<dim3(DIM_ / 256, B_ * 16), 256, 0, stream>>>(x, ps, pss);
  ln_fin<<<dim3((B_ * DIM_) / 256), 256, 0, stream>>>(ps, pss, g, meanA, sclA);
  ln_apply<<<dim3((B_ * N_ * DIM_) / 2048), 256, 0, stream>>>(x, meanA, sclA, xn);
  cast_all<<<dim3(2048), 256, 0, stream>>>(wq, wkv, wout, Wqkv, WoutB);
  gemm_bt<false><<<dim3(3072 / 128, 4096 / 128), 256, 0, stream>>>(xn, Wqkv, qkvb, DIM_, 3072);
  transpose_v<<<dim3(N_ / 64, B_ * HEADS_), 256, 0, stream>>>(qkvb, Vt);
  flash_attn<<<dim3(256), 512, 0, stream>>>(qkvb, bias, Vt, Oatt);
  gemm_bt<true><<<dim3(1024 / 128, 4096 / 128), 256, 0, stream>>>(Oatt, WoutB, out, DIM_, 1024);
}

// Round 21
// 165.876 us; speedup vs baseline: 1.3388x; 1.0156x over previous
//
#include <hip/hip_runtime.h>
#include <hip/hip_bf16.h>
#include <stdint.h>

#define B_ 2
#define N_ 2048
#define DIM_ 1024
#define HEADS_ 16
#define DH_ 64
#define EPS_ 1e-5f

typedef __attribute__((ext_vector_type(4))) float f32x4;
typedef __attribute__((ext_vector_type(8))) float f32x8;
typedef __attribute__((ext_vector_type(16))) float f32x16;
typedef __attribute__((ext_vector_type(8))) __bf16 bf16x8;
typedef __attribute__((ext_vector_type(4))) unsigned int u32x4;
typedef __attribute__((ext_vector_type(2))) unsigned int u32x2;

__device__ __forceinline__ f32x4 mfma16(bf16x8 a, bf16x8 b, f32x4 c) {
  return __builtin_amdgcn_mfma_f32_16x16x32_bf16(a, b, c, 0, 0, 0);
}

__device__ __forceinline__ f32x16 mfma32(bf16x8 a, bf16x8 b, f32x16 c) {
  return __builtin_amdgcn_mfma_f32_32x32x16_bf16(a, b, c, 0, 0, 0);
}

__device__ __forceinline__ unsigned short f2bf(float x) {
  unsigned int u = __builtin_bit_cast(unsigned int, x);
  u += 0x7fffu + ((u >> 16) & 1u);
  return (unsigned short)(u >> 16);
}

__device__ __forceinline__ unsigned int cvt_pk_bf16(float lo, float hi) {
  unsigned int r;
  asm("v_cvt_pk_bf16_f32 %0, %1, %2" : "=v"(r) : "v"(lo), "v"(hi));
  return r;
}

__device__ __forceinline__ float uasf(unsigned int u) { return __builtin_bit_cast(float, u); }
__device__ __forceinline__ unsigned int fasu(float f) { return __builtin_bit_cast(unsigned int, f); }

__device__ __forceinline__ bf16x8 ld_frag(const unsigned short* p) {
  u32x4 v = *reinterpret_cast<const u32x4*>(p);
  return __builtin_bit_cast(bf16x8, v);
}

__device__ __forceinline__ void gload_lds16(const unsigned short* g, unsigned short* l) {
  __builtin_amdgcn_global_load_lds((const __attribute__((address_space(1))) void*)g,
                                   (__attribute__((address_space(3))) void*)l, 16, 0, 0);
}

// ---------------- LayerNorm over sequence axis ----------------
__global__ __launch_bounds__(256) void ln_part(const float* __restrict__ x,
                                               float* __restrict__ ps,
                                               float* __restrict__ pss) {
  const int d = blockIdx.x * 256 + threadIdx.x;
  const int b = blockIdx.y >> 4, sp = blockIdx.y & 15;
  const float* xp = x + (size_t)(b * N_ + sp * 128) * DIM_ + d;
  float s = 0.f, ss = 0.f;
  for (int i = 0; i < 128; ++i) {
    float v = xp[(size_t)i * DIM_];
    s += v;
    ss += v * v;
  }
  int c = b * DIM_ + d;
  ps[sp * (B_ * DIM_) + c] = s;
  pss[sp * (B_ * DIM_) + c] = ss;
}

__global__ void ln_fin(const float* __restrict__ ps, const float* __restrict__ pss,
                       const float* __restrict__ g, float* __restrict__ meanA,
                       float* __restrict__ sclA) {
  int c = blockIdx.x * 256 + threadIdx.x;
  float s = 0.f, ss = 0.f;
#pragma unroll
  for (int sp = 0; sp < 16; ++sp) {
    s += ps[sp * (B_ * DIM_) + c];
    ss += pss[sp * (B_ * DIM_) + c];
  }
  float m = s * (1.f / N_);
  float v = ss * (1.f / N_) - m * m;
  meanA[c] = m;
  sclA[c] = rsqrtf(fmaxf(v, EPS_)) * g[c & (DIM_ - 1)];
}

__global__ __launch_bounds__(256) void ln_apply(const float* __restrict__ x,
                                                const float* __restrict__ meanA,
                                                const float* __restrict__ sclA,
                                                unsigned short* __restrict__ xn) {
  size_t t = (size_t)blockIdx.x * 256 + threadIdx.x;
  size_t base = t * 8;
  int d0 = (int)(base & (DIM_ - 1));
  int b = base >= (size_t)N_ * DIM_;
  int c = b * DIM_ + d0;
  const float4* xp = reinterpret_cast<const float4*>(x + base);
  const float4* mp = reinterpret_cast<const float4*>(meanA + c);
  const float4* sp = reinterpret_cast<const float4*>(sclA + c);
  float4 x0 = xp[0], x1 = xp[1];
  float4 m0 = mp[0], m1 = mp[1];
  float4 s0 = sp[0], s1 = sp[1];
  union {
    unsigned short u[8];
    u32x4 v;
  } o;
  o.u[0] = f2bf((x0.x - m0.x) * s0.x);
  o.u[1] = f2bf((x0.y - m0.y) * s0.y);
  o.u[2] = f2bf((x0.z - m0.z) * s0.z);
  o.u[3] = f2bf((x0.w - m0.w) * s0.w);
  o.u[4] = f2bf((x1.x - m1.x) * s1.x);
  o.u[5] = f2bf((x1.y - m1.y) * s1.y);
  o.u[6] = f2bf((x1.z - m1.z) * s1.z);
  o.u[7] = f2bf((x1.w - m1.w) * s1.w);
  *reinterpret_cast<u32x4*>(xn + base) = o.v;
}

// ---------------- fp32 -> bf16 weight cast, all three weights in one --------
__global__ __launch_bounds__(256) void cast_all(const float* __restrict__ wq,
                                                const float* __restrict__ wkv,
                                                const float* __restrict__ wout,
                                                unsigned short* __restrict__ Wqkv,
                                                unsigned short* __restrict__ WoutB) {
  const int blk = blockIdx.x;
  const float* src;
  unsigned short* dst;
  float scale;
  size_t base;
  if (blk < 512) {
    base = ((size_t)blk * 256 + threadIdx.x) * 8;
    src = wq;
    dst = Wqkv;
    scale = 0.125f;
  } else if (blk < 1536) {
    base = ((size_t)(blk - 512) * 256 + threadIdx.x) * 8;
    src = wkv;
    dst = Wqkv + (size_t)DIM_ * DIM_;
    scale = 1.0f;
  } else {
    base = ((size_t)(blk - 1536) * 256 + threadIdx.x) * 8;
    src = wout;
    dst = WoutB;
    scale = 1.0f;
  }
  const float4* sp = reinterpret_cast<const float4*>(src + base);
  float4 a = sp[0], b4 = sp[1];
  union {
    unsigned short u[8];
    u32x4 v;
  } o;
  o.u[0] = f2bf(a.x * scale);
  o.u[1] = f2bf(a.y * scale);
  o.u[2] = f2bf(a.z * scale);
  o.u[3] = f2bf(a.w * scale);
  o.u[4] = f2bf(b4.x * scale);
  o.u[5] = f2bf(b4.y * scale);
  o.u[6] = f2bf(b4.z * scale);
  o.u[7] = f2bf(b4.w * scale);
  *reinterpret_cast<u32x4*>(dst + base) = o.v;
}

// ---------------- GEMM: C[M,Nc] = A[M,K]bf16 * W[Nc,K]bf16^T ----------------
// V-region blocks (VtOut != nullptr, n0 >= 2048) write TRANSPOSED directly
// into Vt[b][h][dh][n]: acc[i][j][r] holds 4 consecutive rows (n) at fixed
// col -> 8B packed u64 per fragment. Replaces the transpose_v pass entirely.
template <bool OUT_F32>
__global__ __launch_bounds__(256) void gemm_bt(const unsigned short* __restrict__ A,
                                               const unsigned short* __restrict__ W,
                                               void* __restrict__ Cout, int K, int ldc,
                                               unsigned short* __restrict__ VtOut) {
  __shared__ unsigned short sA[128 * 64];
  __shared__ unsigned short sB[128 * 64];
  const int tid = threadIdx.x, lane = tid & 63, w = tid >> 6;
  const int wm = w >> 1, wn = w & 1;
  const int l15 = lane & 15, l4 = lane >> 4;
  const int m0 = blockIdx.y * 128, n0 = blockIdx.x * 128;
  f32x4 acc[4][4] = {};
  for (int kt = 0; kt < K; kt += 64) {
    __syncthreads();
#pragma unroll
    for (int p = 0; p < 4; ++p) {
      int flat = p * 256 + tid;
      int row = flat >> 3, c = flat & 7;
      int cs = c ^ (row & 7);
      gload_lds16(A + (size_t)(m0 + row) * K + kt + cs * 8, sA + (size_t)(p * 256 + w * 64) * 8);
      gload_lds16(W + (size_t)(n0 + row) * K + kt + cs * 8, sB + (size_t)(p * 256 + w * 64) * 8);
    }
    __syncthreads();
#pragma unroll
    for (int kk = 0; kk < 2; ++kk) {
      bf16x8 af[4], bfr[4];
#pragma unroll
      for (int i = 0; i < 4; ++i) {
        int rowA = wm * 64 + i * 16 + l15;
        af[i] = ld_frag(sA + rowA * 64 + (((kk * 4 + l4) ^ (rowA & 7)) * 8));
        int rowB = wn * 64 + i * 16 + l15;
        bfr[i] = ld_frag(sB + rowB * 64 + (((kk * 4 + l4) ^ (rowB & 7)) * 8));
      }
#pragma unroll
      for (int i = 0; i < 4; ++i)
#pragma unroll
        for (int j = 0; j < 4; ++j) acc[i][j] = mfma16(af[i], bfr[j], acc[i][j]);
    }
  }
  if (!OUT_F32 && VtOut != nullptr && n0 >= 2 * DIM_) {
    // transposed V write: col -> (h, dh), 4 consecutive rows -> n..n+3
#pragma unroll
    for (int i = 0; i < 4; ++i)
#pragma unroll
      for (int j = 0; j < 4; ++j) {
        int col = n0 - 2 * DIM_ + wn * 64 + j * 16 + l15;
        int hh = col >> 6, dh = col & 63;
        int row = m0 + wm * 64 + i * 16 + l4 * 4;
        int bb = row >> 11, nn = row & (N_ - 1);
        union {
          unsigned short u[4];
          unsigned long long v;
        } pk;
        pk.u[0] = f2bf(acc[i][j][0]);
        pk.u[1] = f2bf(acc[i][j][1]);
        pk.u[2] = f2bf(acc[i][j][2]);
        pk.u[3] = f2bf(acc[i][j][3]);
        *reinterpret_cast<unsigned long long*>(
            VtOut + ((size_t)(bb * HEADS_ + hh) * 64 + dh) * N_ + nn) = pk.v;
      }
    return;
  }
#pragma unroll
  for (int i = 0; i < 4; ++i)
#pragma unroll
    for (int j = 0; j < 4; ++j)
#pragma unroll
      for (int r = 0; r < 4; ++r) {
        size_t off =
            (size_t)(m0 + wm * 64 + i * 16 + l4 * 4 + r) * ldc + (n0 + wn * 64 + j * 16 + l15);
        if (OUT_F32)
          ((float*)Cout)[off] = acc[i][j][r];
        else
          ((unsigned short*)Cout)[off] = f2bf(acc[i][j][r]);
      }
}

// ---------------- Flash attention: 8 waves, 160KB LDS, 128-key pairs --------
// r12/r19/r20 structure + T13 defer-max (unchanged from round 20).
__global__ __launch_bounds__(512, 2) void flash_attn(const unsigned short* __restrict__ qkv,
                                                     const float* __restrict__ bias,
                                                     const unsigned short* __restrict__ Vt,
                                                     unsigned short* __restrict__ Oatt) {
  __shared__ unsigned short sK[128 * 64];   // 16 KB: pair of K tiles, row=key
  __shared__ unsigned short sV[64 * 128];   // 16 KB: V^T pair, row=d
  __shared__ float sBias[8][32 * 128];      // 128 KB: per-wave 32q x 128k slice

  const int tid = threadIdx.x, lane = tid & 63, w = tid >> 6;  // w in 0..7
  const int l31 = lane & 31, hi = lane >> 5;
  const int r = blockIdx.x;
  const int bh = r & 31, iblk = r >> 5;  // iblk 0..7
  const int h = bh & 15, b = bh >> 4;
  const int qbase = iblk * 256 + w * 32;

  const unsigned short* Kg = qkv + (size_t)b * N_ * 3072 + 1024 + h * 64;
  const unsigned short* VtB = Vt + (size_t)(b * HEADS_ + h) * 64 * N_;
  const float* bias_h = bias + (size_t)h * N_ * N_;

  // ---- K/V staging (cooperative, 2 gload16/thread each) ----
  const int kflat0 = tid, kflat1 = 512 + tid;
  const int krow0 = kflat0 >> 3, kc0 = (kflat0 & 7) ^ (krow0 & 7);
  const int krow1 = kflat1 >> 3, kc1 = (kflat1 & 7) ^ (krow1 & 7);
  const int vrow0 = kflat0 >> 4, vc0 = (kflat0 & 15) ^ (vrow0 & 15);
  const int vrow1 = kflat1 >> 4, vc1 = (kflat1 & 15) ^ (vrow1 & 15);
  unsigned short* sKb0 = sK + (size_t)(w * 64) * 8;
  unsigned short* sKb1 = sK + (size_t)(512 + w * 64) * 8;
  unsigned short* sVb0 = sV + (size_t)(w * 64) * 8;
  unsigned short* sVb1 = sV + (size_t)(512 + w * 64) * 8;

#define STAGE_KV(JN)                                                       \
  gload_lds16(Kg + (size_t)((JN) + krow0) * 3072 + kc0 * 8, sKb0);         \
  gload_lds16(Kg + (size_t)((JN) + krow1) * 3072 + kc1 * 8, sKb1);         \
  gload_lds16(VtB + (size_t)vrow0 * N_ + (JN) + vc0 * 8, sVb0);            \
  gload_lds16(VtB + (size_t)vrow1 * N_ + (JN) + vc1 * 8, sVb1);

  // ---- bias staging: wave-private 32q x 128k, slot s of row r holds ----
  // ---- global chunk s ^ r; dest linear = instr*1024B + lane*16B       ----
  float* sBw = sBias[w];
  unsigned short* sBw_us = reinterpret_cast<unsigned short*>(sBw);
  const int brr = lane >> 5, bsl = lane & 31;
  const float* bQ = bias_h + (size_t)qbase * N_;
#define SBI(i, JN)                                                            \
  gload_lds16((const unsigned short*)(bQ + (size_t)(2 * (i) + brr) * N_ +     \
                                      (JN) + ((bsl ^ (2 * (i) + brr)) << 2)), \
              sBw_us + (i) * 512);
#define STAGE_BIAS(JN)                                                     \
  SBI(0, JN) SBI(1, JN) SBI(2, JN) SBI(3, JN) SBI(4, JN) SBI(5, JN)        \
  SBI(6, JN) SBI(7, JN) SBI(8, JN) SBI(9, JN) SBI(10, JN) SBI(11, JN)      \
  SBI(12, JN) SBI(13, JN) SBI(14, JN) SBI(15, JN)

// C-block from LDS bias: C[rr] = bias[q=l31][CB*4 + 8*(rr>>2)+4*hi+(rr&3)]
#define LDBIAS(DST, CB)                                                        \
  {                                                                            \
    const float* myB_ = sBw + l31 * 128;                                       \
    f32x4 t0 = *reinterpret_cast<const f32x4*>(myB_ + ((((CB) + 0 + hi) ^ l31) << 2)); \
    f32x4 t1 = *reinterpret_cast<const f32x4*>(myB_ + ((((CB) + 2 + hi) ^ l31) << 2)); \
    f32x4 t2 = *reinterpret_cast<const f32x4*>(myB_ + ((((CB) + 4 + hi) ^ l31) << 2)); \
    f32x4 t3 = *reinterpret_cast<const f32x4*>(myB_ + ((((CB) + 6 + hi) ^ l31) << 2)); \
    f32x8 u0_ = __builtin_shufflevector(t0, t1, 0, 1, 2, 3, 4, 5, 6, 7);       \
    f32x8 u1_ = __builtin_shufflevector(t2, t3, 0, 1, 2, 3, 4, 5, 6, 7);       \
    DST = __builtin_shufflevector(u0_, u1_, 0, 1, 2, 3, 4, 5, 6, 7, 8, 9, 10,  \
                                  11, 12, 13, 14, 15);                         \
  }

#define FRAGK(OUT, ROWB, CH)                                              \
  {                                                                       \
    int row_ = (ROWB) + l31;                                              \
    OUT = ld_frag(sK + row_ * 64 + (((CH) ^ (row_ & 7)) * 8));            \
  }
#define FRAGV(OUT, ROWB, CH)                                              \
  {                                                                       \
    int row_ = (ROWB) + l31;                                              \
    OUT = ld_frag(sV + row_ * 128 + (((CH) ^ (row_ & 15)) * 8));          \
  }

// pack one 32-key S block into two PV B-frags (verified r9/r10/r12)
#define PACK2(S, PLO, PHI)                                                 \
  {                                                                        \
    unsigned int w0 = cvt_pk_bf16(S[0], S[1]), w1 = cvt_pk_bf16(S[2], S[3]);     \
    unsigned int w2 = cvt_pk_bf16(S[4], S[5]), w3 = cvt_pk_bf16(S[6], S[7]);     \
    unsigned int w4 = cvt_pk_bf16(S[8], S[9]), w5 = cvt_pk_bf16(S[10], S[11]);   \
    unsigned int w6 = cvt_pk_bf16(S[12], S[13]), w7 = cvt_pk_bf16(S[14], S[15]); \
    auto rA = __builtin_amdgcn_permlane32_swap(w0, w2, false, false);      \
    auto rB = __builtin_amdgcn_permlane32_swap(w1, w3, false, false);      \
    auto rC = __builtin_amdgcn_permlane32_swap(w4, w6, false, false);      \
    auto rD = __builtin_amdgcn_permlane32_swap(w5, w7, false, false);      \
    u32x4 pw;                                                              \
    pw[0] = rA[0]; pw[1] = rB[0]; pw[2] = rA[1]; pw[3] = rB[1];            \
    PLO = __builtin_bit_cast(bf16x8, pw);                                  \
    pw[0] = rC[0]; pw[1] = rD[0]; pw[2] = rC[1]; pw[3] = rD[1];            \
    PHI = __builtin_bit_cast(bf16x8, pw);                                  \
  }

  // Q B-frags: qfK covers d = K*16 + hi*8 .. +7 for q = qbase + l31
  bf16x8 qf0, qf1, qf2, qf3;
  {
    const unsigned short* Qg =
        qkv + (size_t)(b * N_ + qbase + l31) * 3072 + h * 64 + hi * 8;
    qf0 = ld_frag(Qg);
    qf1 = ld_frag(Qg + 16);
    qf2 = ld_frag(Qg + 32);
    qf3 = ld_frag(Qg + 48);
  }

  f32x16 o0 = {}, o1 = {};
  float m_run = -1e30f, l_run = 0.f;

  // prologue: stage pair 0 (drained at loop-top vmcnt(0))
  STAGE_KV(0)
  STAGE_BIAS(0)

  const int NP = N_ / 128;  // 16 pairs
  for (int p = 0; p < NP; ++p) {
    asm volatile("s_waitcnt vmcnt(0) lgkmcnt(0)" ::: "memory");
    __builtin_amdgcn_s_barrier();

    // 1. bias regs for pair p (C-operands for the 4 S blocks)
    f32x16 SA0, SA1, SB0, SB1;
    LDBIAS(SA0, 0)
    LDBIAS(SA1, 8)
    LDBIAS(SB0, 16)
    LDBIAS(SB1, 24)
    asm volatile("s_waitcnt lgkmcnt(0)" ::: "memory");
    __builtin_amdgcn_sched_barrier(0);  // bias regs live before overwrite

    // 2. bias prefetch for pair p+1 (full-pair cover; wave-private slice)
    if (p + 1 < NP) {
      const size_t jn = (size_t)(p + 1) * 128;
      STAGE_BIAS(jn)
    }

    // 3. S^T = K Q^T + bias for both tiles of the pair
    __builtin_amdgcn_s_setprio(1);
    {
      bf16x8 kf;
      FRAGK(kf, 0, 0 + hi)  SA0 = mfma32(kf, qf0, SA0);
      FRAGK(kf, 0, 2 + hi)  SA0 = mfma32(kf, qf1, SA0);
      FRAGK(kf, 0, 4 + hi)  SA0 = mfma32(kf, qf2, SA0);
      FRAGK(kf, 0, 6 + hi)  SA0 = mfma32(kf, qf3, SA0);
      FRAGK(kf, 32, 0 + hi) SA1 = mfma32(kf, qf0, SA1);
      FRAGK(kf, 32, 2 + hi) SA1 = mfma32(kf, qf1, SA1);
      FRAGK(kf, 32, 4 + hi) SA1 = mfma32(kf, qf2, SA1);
      FRAGK(kf, 32, 6 + hi) SA1 = mfma32(kf, qf3, SA1);
      FRAGK(kf, 64, 0 + hi) SB0 = mfma32(kf, qf0, SB0);
      FRAGK(kf, 64, 2 + hi) SB0 = mfma32(kf, qf1, SB0);
      FRAGK(kf, 64, 4 + hi) SB0 = mfma32(kf, qf2, SB0);
      FRAGK(kf, 64, 6 + hi) SB0 = mfma32(kf, qf3, SB0);
      FRAGK(kf, 96, 0 + hi) SB1 = mfma32(kf, qf0, SB1);
      FRAGK(kf, 96, 2 + hi) SB1 = mfma32(kf, qf1, SB1);
      FRAGK(kf, 96, 4 + hi) SB1 = mfma32(kf, qf2, SB1);
      FRAGK(kf, 96, 6 + hi) SB1 = mfma32(kf, qf3, SB1);
    }
    __builtin_amdgcn_s_setprio(0);

    // 4. merged online softmax over 128 keys, T13 defer-max (THR=8)
    float c0 = SA0[0], c1 = SA1[0], c2 = SB0[0], c3 = SB1[0];
#pragma unroll
    for (int i = 1; i < 16; ++i) {
      c0 = fmaxf(c0, SA0[i]);
      c1 = fmaxf(c1, SA1[i]);
      c2 = fmaxf(c2, SB0[i]);
      c3 = fmaxf(c3, SB1[i]);
    }
    float mx = fmaxf(fmaxf(c0, c1), fmaxf(c2, c3));
    {
      auto pr_ = __builtin_amdgcn_permlane32_swap(fasu(mx), fasu(mx), false, false);
      mx = fmaxf(uasf(pr_[0]), uasf(pr_[1]));
    }
    if (!__all(mx <= m_run + 8.f)) {
      float mn = fmaxf(m_run, mx);
      float alpha = __expf(m_run - mn);
      l_run *= alpha;
#pragma unroll
      for (int i = 0; i < 16; ++i) {
        o0[i] *= alpha;
        o1[i] *= alpha;
      }
      m_run = mn;
    }
#pragma unroll
    for (int i = 0; i < 16; ++i) {
      SA0[i] = __expf(SA0[i] - m_run);
      SA1[i] = __expf(SA1[i] - m_run);
      SB0[i] = __expf(SB0[i] - m_run);
      SB1[i] = __expf(SB1[i] - m_run);
    }
    float r0 = 0.f, r1 = 0.f, r2 = 0.f, r3 = 0.f;
#pragma unroll
    for (int i = 0; i < 16; ++i) {
      r0 += SA0[i];
      r1 += SA1[i];
      r2 += SB0[i];
      r3 += SB1[i];
    }
    float rs = (r0 + r1) + (r2 + r3);
    {
      auto pr_ = __builtin_amdgcn_permlane32_swap(fasu(rs), fasu(rs), false, false);
      rs = uasf(pr_[0]) + uasf(pr_[1]);
    }
    l_run = l_run + rs;

    // 5. P -> PV B-frags in-register
    bf16x8 pA0, pA1, pA2, pA3, pB0, pB1, pB2, pB3;
    PACK2(SA0, pA0, pA1)
    PACK2(SA1, pA2, pA3)
    PACK2(SB0, pB0, pB1)
    PACK2(SB1, pB2, pB3)

    // 6. O^T += V^T P^T over the 128-key pair
    __builtin_amdgcn_s_setprio(1);
    {
      bf16x8 vf;
      FRAGV(vf, 0, 0 + hi)   o0 = mfma32(vf, pA0, o0);
      FRAGV(vf, 0, 2 + hi)   o0 = mfma32(vf, pA1, o0);
      FRAGV(vf, 0, 4 + hi)   o0 = mfma32(vf, pA2, o0);
      FRAGV(vf, 0, 6 + hi)   o0 = mfma32(vf, pA3, o0);
      FRAGV(vf, 0, 8 + hi)   o0 = mfma32(vf, pB0, o0);
      FRAGV(vf, 0, 10 + hi)  o0 = mfma32(vf, pB1, o0);
      FRAGV(vf, 0, 12 + hi)  o0 = mfma32(vf, pB2, o0);
      FRAGV(vf, 0, 14 + hi)  o0 = mfma32(vf, pB3, o0);
      FRAGV(vf, 32, 0 + hi)  o1 = mfma32(vf, pA0, o1);
      FRAGV(vf, 32, 2 + hi)  o1 = mfma32(vf, pA1, o1);
      FRAGV(vf, 32, 4 + hi)  o1 = mfma32(vf, pA2, o1);
      FRAGV(vf, 32, 6 + hi)  o1 = mfma32(vf, pA3, o1);
      FRAGV(vf, 32, 8 + hi)  o1 = mfma32(vf, pB0, o1);
      FRAGV(vf, 32, 10 + hi) o1 = mfma32(vf, pB1, o1);
      FRAGV(vf, 32, 12 + hi) o1 = mfma32(vf, pB2, o1);
      FRAGV(vf, 32, 14 + hi) o1 = mfma32(vf, pB3, o1);
    }
    __builtin_amdgcn_s_setprio(0);

    // 7. all waves done reading K/V pair p -> stage pair p+1
    asm volatile("s_waitcnt lgkmcnt(0)" ::: "memory");
    __builtin_amdgcn_s_barrier();
    if (p + 1 < NP) {
      const size_t jn = (size_t)(p + 1) * 128;
      STAGE_KV(jn)
    }
  }
#undef STAGE_KV
#undef SBI
#undef STAGE_BIAS
#undef LDBIAS
#undef FRAGK
#undef FRAGV
#undef PACK2

  // epilogue: O[q][d] = O^T / l
  float inv = 1.f / l_run;
  unsigned short* orow =
      Oatt + (size_t)(b * N_ + qbase + l31) * 1024 + h * 64 + hi * 4;
#pragma unroll
  for (int g = 0; g < 4; ++g) {
    u32x2 pk0;
    pk0[0] = cvt_pk_bf16(o0[g * 4 + 0] * inv, o0[g * 4 + 1] * inv);
    pk0[1] = cvt_pk_bf16(o0[g * 4 + 2] * inv, o0[g * 4 + 3] * inv);
    *reinterpret_cast<u32x2*>(orow + g * 8) = pk0;
    u32x2 pk1;
    pk1[0] = cvt_pk_bf16(o1[g * 4 + 0] * inv, o1[g * 4 + 1] * inv);
    pk1[1] = cvt_pk_bf16(o1[g * 4 + 2] * inv, o1[g * 4 + 3] * inv);
    *reinterpret_cast<u32x2*>(orow + 32 + g * 8) = pk1;
  }
}

extern "C" void kernel_launch(void* const* d_in, const int* in_sizes, int n_in, void* d_out,
                              int out_size, void* d_ws, size_t ws_size, hipStream_t stream) {
  const float* x = (const float*)d_in[0];
  const float* bias = (const float*)d_in[1];
  const float* g = (const float*)d_in[2];
  const float* wq = (const float*)d_in[3];
  const float* wkv = (const float*)d_in[4];
  const float* wout = (const float*)d_in[5];
  float* out = (float*)d_out;

  float* ps = (float*)d_ws;
  float* pss = ps + 16 * B_ * DIM_;
  float* meanA = pss + 16 * B_ * DIM_;
  float* sclA = meanA + B_ * DIM_;
  unsigned short* xn = (unsigned short*)(sclA + B_ * DIM_);
  unsigned short* Wqkv = xn + (size_t)4096 * 1024;
  unsigned short* WoutB = Wqkv + (size_t)3072 * 1024;
  unsigned short* qkvb = WoutB + (size_t)1024 * 1024;
  unsigned short* Vt = qkvb + (size_t)4096 * 3072;
  unsigned short* Oatt = xn;  // alias: xn dead after QKV GEMM

  ln_part<<<dim3(DIM_ / 256, B_ * 16), 256, 0, stream>>>(x, ps, pss);
  ln_fin<<<dim3((B_ * DIM_) / 256), 256, 0, stream>>>(ps, pss, g, meanA, sclA);
  ln_apply<<<dim3((B_ * N_ * DIM_) / 2048), 256, 0, stream>>>(x, meanA, sclA, xn);
  cast_all<<<dim3(2048), 256, 0, stream>>>(wq, wkv, wout, Wqkv, WoutB);
  gemm_bt<false><<<dim3(3072 / 128, 4096 / 128), 256, 0, stream>>>(xn, Wqkv, qkvb, DIM_, 3072,
                                                                   Vt);
  flash_attn<<<dim3(256), 512, 0, stream>>>(qkvb, bias, Vt, Oatt);
  gemm_bt<true><<<dim3(1024 / 128, 4096 / 128), 256, 0, stream>>>(Oatt, WoutB, out, DIM_, 1024,
                                                                  nullptr);
}

// Round 22
// 161.650 us; speedup vs baseline: 1.3738x; 1.0261x over previous
//
#include <hip/hip_runtime.h>
#include <hip/hip_bf16.h>
#include <stdint.h>

#define B_ 2
#define N_ 2048
#define DIM_ 1024
#define HEADS_ 16
#define DH_ 64
#define EPS_ 1e-5f

typedef __attribute__((ext_vector_type(4))) float f32x4;
typedef __attribute__((ext_vector_type(8))) float f32x8;
typedef __attribute__((ext_vector_type(16))) float f32x16;
typedef __attribute__((ext_vector_type(8))) __bf16 bf16x8;
typedef __attribute__((ext_vector_type(4))) unsigned int u32x4;
typedef __attribute__((ext_vector_type(2))) unsigned int u32x2;

__device__ __forceinline__ f32x4 mfma16(bf16x8 a, bf16x8 b, f32x4 c) {
  return __builtin_amdgcn_mfma_f32_16x16x32_bf16(a, b, c, 0, 0, 0);
}

__device__ __forceinline__ f32x16 mfma32(bf16x8 a, bf16x8 b, f32x16 c) {
  return __builtin_amdgcn_mfma_f32_32x32x16_bf16(a, b, c, 0, 0, 0);
}

__device__ __forceinline__ unsigned short f2bf(float x) {
  unsigned int u = __builtin_bit_cast(unsigned int, x);
  u += 0x7fffu + ((u >> 16) & 1u);
  return (unsigned short)(u >> 16);
}

__device__ __forceinline__ unsigned int cvt_pk_bf16(float lo, float hi) {
  unsigned int r;
  asm("v_cvt_pk_bf16_f32 %0, %1, %2" : "=v"(r) : "v"(lo), "v"(hi));
  return r;
}

__device__ __forceinline__ float uasf(unsigned int u) { return __builtin_bit_cast(float, u); }
__device__ __forceinline__ unsigned int fasu(float f) { return __builtin_bit_cast(unsigned int, f); }

__device__ __forceinline__ bf16x8 ld_frag(const unsigned short* p) {
  u32x4 v = *reinterpret_cast<const u32x4*>(p);
  return __builtin_bit_cast(bf16x8, v);
}

__device__ __forceinline__ void gload_lds16(const unsigned short* g, unsigned short* l) {
  __builtin_amdgcn_global_load_lds((const __attribute__((address_space(1))) void*)g,
                                   (__attribute__((address_space(3))) void*)l, 16, 0, 0);
}

// ---------------- fused: LN partial sums (blocks 0..127) + weight casts -----
// Independent workloads sharing one launch; branch is block-uniform.
//   blocks [0,128):     ln_part  (bx = blk & 3, by = blk >> 2)
//   blocks [128,640):   wq cast (scale 0.125) -> Wqkv[0..)
//   blocks [640,1664):  wkv cast              -> Wqkv[1M..)
//   blocks [1664,2176): wout cast             -> WoutB
__global__ __launch_bounds__(256) void pre_fused(const float* __restrict__ x,
                                                 float* __restrict__ ps,
                                                 float* __restrict__ pss,
                                                 const float* __restrict__ wq,
                                                 const float* __restrict__ wkv,
                                                 const float* __restrict__ wout,
                                                 unsigned short* __restrict__ Wqkv,
                                                 unsigned short* __restrict__ WoutB) {
  const int blk = blockIdx.x;
  if (blk < 128) {
    const int d = (blk & 3) * 256 + threadIdx.x;
    const int by = blk >> 2;
    const int b = by >> 4, sp = by & 15;
    const float* xp = x + (size_t)(b * N_ + sp * 128) * DIM_ + d;
    float s = 0.f, ss = 0.f;
    for (int i = 0; i < 128; ++i) {
      float v = xp[(size_t)i * DIM_];
      s += v;
      ss += v * v;
    }
    int c = b * DIM_ + d;
    ps[sp * (B_ * DIM_) + c] = s;
    pss[sp * (B_ * DIM_) + c] = ss;
    return;
  }
  const int cb = blk - 128;
  const float* src;
  unsigned short* dst;
  float scale;
  size_t base;
  if (cb < 512) {
    base = ((size_t)cb * 256 + threadIdx.x) * 8;
    src = wq;
    dst = Wqkv;
    scale = 0.125f;
  } else if (cb < 1536) {
    base = ((size_t)(cb - 512) * 256 + threadIdx.x) * 8;
    src = wkv;
    dst = Wqkv + (size_t)DIM_ * DIM_;
    scale = 1.0f;
  } else {
    base = ((size_t)(cb - 1536) * 256 + threadIdx.x) * 8;
    src = wout;
    dst = WoutB;
    scale = 1.0f;
  }
  const float4* sp = reinterpret_cast<const float4*>(src + base);
  float4 a = sp[0], b4 = sp[1];
  union {
    unsigned short u[8];
    u32x4 v;
  } o;
  o.u[0] = f2bf(a.x * scale);
  o.u[1] = f2bf(a.y * scale);
  o.u[2] = f2bf(a.z * scale);
  o.u[3] = f2bf(a.w * scale);
  o.u[4] = f2bf(b4.x * scale);
  o.u[5] = f2bf(b4.y * scale);
  o.u[6] = f2bf(b4.z * scale);
  o.u[7] = f2bf(b4.w * scale);
  *reinterpret_cast<u32x4*>(dst + base) = o.v;
}

__global__ void ln_fin(const float* __restrict__ ps, const float* __restrict__ pss,
                       const float* __restrict__ g, float* __restrict__ meanA,
                       float* __restrict__ sclA) {
  int c = blockIdx.x * 256 + threadIdx.x;
  float s = 0.f, ss = 0.f;
#pragma unroll
  for (int sp = 0; sp < 16; ++sp) {
    s += ps[sp * (B_ * DIM_) + c];
    ss += pss[sp * (B_ * DIM_) + c];
  }
  float m = s * (1.f / N_);
  float v = ss * (1.f / N_) - m * m;
  meanA[c] = m;
  sclA[c] = rsqrtf(fmaxf(v, EPS_)) * g[c & (DIM_ - 1)];
}

__global__ __launch_bounds__(256) void ln_apply(const float* __restrict__ x,
                                                const float* __restrict__ meanA,
                                                const float* __restrict__ sclA,
                                                unsigned short* __restrict__ xn) {
  size_t t = (size_t)blockIdx.x * 256 + threadIdx.x;
  size_t base = t * 8;
  int d0 = (int)(base & (DIM_ - 1));
  int b = base >= (size_t)N_ * DIM_;
  int c = b * DIM_ + d0;
  const float4* xp = reinterpret_cast<const float4*>(x + base);
  const float4* mp = reinterpret_cast<const float4*>(meanA + c);
  const float4* sp = reinterpret_cast<const float4*>(sclA + c);
  float4 x0 = xp[0], x1 = xp[1];
  float4 m0 = mp[0], m1 = mp[1];
  float4 s0 = sp[0], s1 = sp[1];
  union {
    unsigned short u[8];
    u32x4 v;
  } o;
  o.u[0] = f2bf((x0.x - m0.x) * s0.x);
  o.u[1] = f2bf((x0.y - m0.y) * s0.y);
  o.u[2] = f2bf((x0.z - m0.z) * s0.z);
  o.u[3] = f2bf((x0.w - m0.w) * s0.w);
  o.u[4] = f2bf((x1.x - m1.x) * s1.x);
  o.u[5] = f2bf((x1.y - m1.y) * s1.y);
  o.u[6] = f2bf((x1.z - m1.z) * s1.z);
  o.u[7] = f2bf((x1.w - m1.w) * s1.w);
  *reinterpret_cast<u32x4*>(xn + base) = o.v;
}

// ---------------- GEMM: C[M,Nc] = A[M,K]bf16 * W[Nc,K]bf16^T ----------------
// V-region blocks (VtOut != nullptr, n0 >= 2048) write TRANSPOSED directly
// into Vt[b][h][dh][n] (r21-verified).
template <bool OUT_F32>
__global__ __launch_bounds__(256) void gemm_bt(const unsigned short* __restrict__ A,
                                               const unsigned short* __restrict__ W,
                                               void* __restrict__ Cout, int K, int ldc,
                                               unsigned short* __restrict__ VtOut) {
  __shared__ unsigned short sA[128 * 64];
  __shared__ unsigned short sB[128 * 64];
  const int tid = threadIdx.x, lane = tid & 63, w = tid >> 6;
  const int wm = w >> 1, wn = w & 1;
  const int l15 = lane & 15, l4 = lane >> 4;
  const int m0 = blockIdx.y * 128, n0 = blockIdx.x * 128;
  f32x4 acc[4][4] = {};
  for (int kt = 0; kt < K; kt += 64) {
    __syncthreads();
#pragma unroll
    for (int p = 0; p < 4; ++p) {
      int flat = p * 256 + tid;
      int row = flat >> 3, c = flat & 7;
      int cs = c ^ (row & 7);
      gload_lds16(A + (size_t)(m0 + row) * K + kt + cs * 8, sA + (size_t)(p * 256 + w * 64) * 8);
      gload_lds16(W + (size_t)(n0 + row) * K + kt + cs * 8, sB + (size_t)(p * 256 + w * 64) * 8);
    }
    __syncthreads();
#pragma unroll
    for (int kk = 0; kk < 2; ++kk) {
      bf16x8 af[4], bfr[4];
#pragma unroll
      for (int i = 0; i < 4; ++i) {
        int rowA = wm * 64 + i * 16 + l15;
        af[i] = ld_frag(sA + rowA * 64 + (((kk * 4 + l4) ^ (rowA & 7)) * 8));
        int rowB = wn * 64 + i * 16 + l15;
        bfr[i] = ld_frag(sB + rowB * 64 + (((kk * 4 + l4) ^ (rowB & 7)) * 8));
      }
#pragma unroll
      for (int i = 0; i < 4; ++i)
#pragma unroll
        for (int j = 0; j < 4; ++j) acc[i][j] = mfma16(af[i], bfr[j], acc[i][j]);
    }
  }
  if (!OUT_F32 && VtOut != nullptr && n0 >= 2 * DIM_) {
#pragma unroll
    for (int i = 0; i < 4; ++i)
#pragma unroll
      for (int j = 0; j < 4; ++j) {
        int col = n0 - 2 * DIM_ + wn * 64 + j * 16 + l15;
        int hh = col >> 6, dh = col & 63;
        int row = m0 + wm * 64 + i * 16 + l4 * 4;
        int bb = row >> 11, nn = row & (N_ - 1);
        union {
          unsigned short u[4];
          unsigned long long v;
        } pk;
        pk.u[0] = f2bf(acc[i][j][0]);
        pk.u[1] = f2bf(acc[i][j][1]);
        pk.u[2] = f2bf(acc[i][j][2]);
        pk.u[3] = f2bf(acc[i][j][3]);
        *reinterpret_cast<unsigned long long*>(
            VtOut + ((size_t)(bb * HEADS_ + hh) * 64 + dh) * N_ + nn) = pk.v;
      }
    return;
  }
#pragma unroll
  for (int i = 0; i < 4; ++i)
#pragma unroll
    for (int j = 0; j < 4; ++j)
#pragma unroll
      for (int r = 0; r < 4; ++r) {
        size_t off =
            (size_t)(m0 + wm * 64 + i * 16 + l4 * 4 + r) * ldc + (n0 + wn * 64 + j * 16 + l15);
        if (OUT_F32)
          ((float*)Cout)[off] = acc[i][j][r];
        else
          ((unsigned short*)Cout)[off] = f2bf(acc[i][j][r]);
      }
}

// ---------------- Flash attention: 8 waves, 160KB LDS, 128-key pairs --------
// r12/r19/r20 structure + T13 defer-max (unchanged from rounds 20/21).
__global__ __launch_bounds__(512, 2) void flash_attn(const unsigned short* __restrict__ qkv,
                                                     const float* __restrict__ bias,
                                                     const unsigned short* __restrict__ Vt,
                                                     unsigned short* __restrict__ Oatt) {
  __shared__ unsigned short sK[128 * 64];   // 16 KB: pair of K tiles, row=key
  __shared__ unsigned short sV[64 * 128];   // 16 KB: V^T pair, row=d
  __shared__ float sBias[8][32 * 128];      // 128 KB: per-wave 32q x 128k slice

  const int tid = threadIdx.x, lane = tid & 63, w = tid >> 6;  // w in 0..7
  const int l31 = lane & 31, hi = lane >> 5;
  const int r = blockIdx.x;
  const int bh = r & 31, iblk = r >> 5;  // iblk 0..7
  const int h = bh & 15, b = bh >> 4;
  const int qbase = iblk * 256 + w * 32;

  const unsigned short* Kg = qkv + (size_t)b * N_ * 3072 + 1024 + h * 64;
  const unsigned short* VtB = Vt + (size_t)(b * HEADS_ + h) * 64 * N_;
  const float* bias_h = bias + (size_t)h * N_ * N_;

  // ---- K/V staging (cooperative, 2 gload16/thread each) ----
  const int kflat0 = tid, kflat1 = 512 + tid;
  const int krow0 = kflat0 >> 3, kc0 = (kflat0 & 7) ^ (krow0 & 7);
  const int krow1 = kflat1 >> 3, kc1 = (kflat1 & 7) ^ (krow1 & 7);
  const int vrow0 = kflat0 >> 4, vc0 = (kflat0 & 15) ^ (vrow0 & 15);
  const int vrow1 = kflat1 >> 4, vc1 = (kflat1 & 15) ^ (vrow1 & 15);
  unsigned short* sKb0 = sK + (size_t)(w * 64) * 8;
  unsigned short* sKb1 = sK + (size_t)(512 + w * 64) * 8;
  unsigned short* sVb0 = sV + (size_t)(w * 64) * 8;
  unsigned short* sVb1 = sV + (size_t)(512 + w * 64) * 8;

#define STAGE_KV(JN)                                                       \
  gload_lds16(Kg + (size_t)((JN) + krow0) * 3072 + kc0 * 8, sKb0);         \
  gload_lds16(Kg + (size_t)((JN) + krow1) * 3072 + kc1 * 8, sKb1);         \
  gload_lds16(VtB + (size_t)vrow0 * N_ + (JN) + vc0 * 8, sVb0);            \
  gload_lds16(VtB + (size_t)vrow1 * N_ + (JN) + vc1 * 8, sVb1);

  // ---- bias staging: wave-private 32q x 128k, slot s of row r holds ----
  // ---- global chunk s ^ r; dest linear = instr*1024B + lane*16B       ----
  float* sBw = sBias[w];
  unsigned short* sBw_us = reinterpret_cast<unsigned short*>(sBw);
  const int brr = lane >> 5, bsl = lane & 31;
  const float* bQ = bias_h + (size_t)qbase * N_;
#define SBI(i, JN)                                                            \
  gload_lds16((const unsigned short*)(bQ + (size_t)(2 * (i) + brr) * N_ +     \
                                      (JN) + ((bsl ^ (2 * (i) + brr)) << 2)), \
              sBw_us + (i) * 512);
#define STAGE_BIAS(JN)                                                     \
  SBI(0, JN) SBI(1, JN) SBI(2, JN) SBI(3, JN) SBI(4, JN) SBI(5, JN)        \
  SBI(6, JN) SBI(7, JN) SBI(8, JN) SBI(9, JN) SBI(10, JN) SBI(11, JN)      \
  SBI(12, JN) SBI(13, JN) SBI(14, JN) SBI(15, JN)

// C-block from LDS bias: C[rr] = bias[q=l31][CB*4 + 8*(rr>>2)+4*hi+(rr&3)]
#define LDBIAS(DST, CB)                                                        \
  {                                                                            \
    const float* myB_ = sBw + l31 * 128;                                       \
    f32x4 t0 = *reinterpret_cast<const f32x4*>(myB_ + ((((CB) + 0 + hi) ^ l31) << 2)); \
    f32x4 t1 = *reinterpret_cast<const f32x4*>(myB_ + ((((CB) + 2 + hi) ^ l31) << 2)); \
    f32x4 t2 = *reinterpret_cast<const f32x4*>(myB_ + ((((CB) + 4 + hi) ^ l31) << 2)); \
    f32x4 t3 = *reinterpret_cast<const f32x4*>(myB_ + ((((CB) + 6 + hi) ^ l31) << 2)); \
    f32x8 u0_ = __builtin_shufflevector(t0, t1, 0, 1, 2, 3, 4, 5, 6, 7);       \
    f32x8 u1_ = __builtin_shufflevector(t2, t3, 0, 1, 2, 3, 4, 5, 6, 7);       \
    DST = __builtin_shufflevector(u0_, u1_, 0, 1, 2, 3, 4, 5, 6, 7, 8, 9, 10,  \
                                  11, 12, 13, 14, 15);                         \
  }

#define FRAGK(OUT, ROWB, CH)                                              \
  {                                                                       \
    int row_ = (ROWB) + l31;                                              \
    OUT = ld_frag(sK + row_ * 64 + (((CH) ^ (row_ & 7)) * 8));            \
  }
#define FRAGV(OUT, ROWB, CH)                                              \
  {                                                                       \
    int row_ = (ROWB) + l31;                                              \
    OUT = ld_frag(sV + row_ * 128 + (((CH) ^ (row_ & 15)) * 8));          \
  }

// pack one 32-key S block into two PV B-frags (verified r9/r10/r12)
#define PACK2(S, PLO, PHI)                                                 \
  {                                                                        \
    unsigned int w0 = cvt_pk_bf16(S[0], S[1]), w1 = cvt_pk_bf16(S[2], S[3]);     \
    unsigned int w2 = cvt_pk_bf16(S[4], S[5]), w3 = cvt_pk_bf16(S[6], S[7]);     \
    unsigned int w4 = cvt_pk_bf16(S[8], S[9]), w5 = cvt_pk_bf16(S[10], S[11]);   \
    unsigned int w6 = cvt_pk_bf16(S[12], S[13]), w7 = cvt_pk_bf16(S[14], S[15]); \
    auto rA = __builtin_amdgcn_permlane32_swap(w0, w2, false, false);      \
    auto rB = __builtin_amdgcn_permlane32_swap(w1, w3, false, false);      \
    auto rC = __builtin_amdgcn_permlane32_swap(w4, w6, false, false);      \
    auto rD = __builtin_amdgcn_permlane32_swap(w5, w7, false, false);      \
    u32x4 pw;                                                              \
    pw[0] = rA[0]; pw[1] = rB[0]; pw[2] = rA[1]; pw[3] = rB[1];            \
    PLO = __builtin_bit_cast(bf16x8, pw);                                  \
    pw[0] = rC[0]; pw[1] = rD[0]; pw[2] = rC[1]; pw[3] = rD[1];            \
    PHI = __builtin_bit_cast(bf16x8, pw);                                  \
  }

  // Q B-frags: qfK covers d = K*16 + hi*8 .. +7 for q = qbase + l31
  bf16x8 qf0, qf1, qf2, qf3;
  {
    const unsigned short* Qg =
        qkv + (size_t)(b * N_ + qbase + l31) * 3072 + h * 64 + hi * 8;
    qf0 = ld_frag(Qg);
    qf1 = ld_frag(Qg + 16);
    qf2 = ld_frag(Qg + 32);
    qf3 = ld_frag(Qg + 48);
  }

  f32x16 o0 = {}, o1 = {};
  float m_run = -1e30f, l_run = 0.f;

  // prologue: stage pair 0 (drained at loop-top vmcnt(0))
  STAGE_KV(0)
  STAGE_BIAS(0)

  const int NP = N_ / 128;  // 16 pairs
  for (int p = 0; p < NP; ++p) {
    asm volatile("s_waitcnt vmcnt(0) lgkmcnt(0)" ::: "memory");
    __builtin_amdgcn_s_barrier();

    // 1. bias regs for pair p (C-operands for the 4 S blocks)
    f32x16 SA0, SA1, SB0, SB1;
    LDBIAS(SA0, 0)
    LDBIAS(SA1, 8)
    LDBIAS(SB0, 16)
    LDBIAS(SB1, 24)
    asm volatile("s_waitcnt lgkmcnt(0)" ::: "memory");
    __builtin_amdgcn_sched_barrier(0);  // bias regs live before overwrite

    // 2. bias prefetch for pair p+1 (full-pair cover; wave-private slice)
    if (p + 1 < NP) {
      const size_t jn = (size_t)(p + 1) * 128;
      STAGE_BIAS(jn)
    }

    // 3. S^T = K Q^T + bias for both tiles of the pair
    __builtin_amdgcn_s_setprio(1);
    {
      bf16x8 kf;
      FRAGK(kf, 0, 0 + hi)  SA0 = mfma32(kf, qf0, SA0);
      FRAGK(kf, 0, 2 + hi)  SA0 = mfma32(kf, qf1, SA0);
      FRAGK(kf, 0, 4 + hi)  SA0 = mfma32(kf, qf2, SA0);
      FRAGK(kf, 0, 6 + hi)  SA0 = mfma32(kf, qf3, SA0);
      FRAGK(kf, 32, 0 + hi) SA1 = mfma32(kf, qf0, SA1);
      FRAGK(kf, 32, 2 + hi) SA1 = mfma32(kf, qf1, SA1);
      FRAGK(kf, 32, 4 + hi) SA1 = mfma32(kf, qf2, SA1);
      FRAGK(kf, 32, 6 + hi) SA1 = mfma32(kf, qf3, SA1);
      FRAGK(kf, 64, 0 + hi) SB0 = mfma32(kf, qf0, SB0);
      FRAGK(kf, 64, 2 + hi) SB0 = mfma32(kf, qf1, SB0);
      FRAGK(kf, 64, 4 + hi) SB0 = mfma32(kf, qf2, SB0);
      FRAGK(kf, 64, 6 + hi) SB0 = mfma32(kf, qf3, SB0);
      FRAGK(kf, 96, 0 + hi) SB1 = mfma32(kf, qf0, SB1);
      FRAGK(kf, 96, 2 + hi) SB1 = mfma32(kf, qf1, SB1);
      FRAGK(kf, 96, 4 + hi) SB1 = mfma32(kf, qf2, SB1);
      FRAGK(kf, 96, 6 + hi) SB1 = mfma32(kf, qf3, SB1);
    }
    __builtin_amdgcn_s_setprio(0);

    // 4. merged online softmax over 128 keys, T13 defer-max (THR=8)
    float c0 = SA0[0], c1 = SA1[0], c2 = SB0[0], c3 = SB1[0];
#pragma unroll
    for (int i = 1; i < 16; ++i) {
      c0 = fmaxf(c0, SA0[i]);
      c1 = fmaxf(c1, SA1[i]);
      c2 = fmaxf(c2, SB0[i]);
      c3 = fmaxf(c3, SB1[i]);
    }
    float mx = fmaxf(fmaxf(c0, c1), fmaxf(c2, c3));
    {
      auto pr_ = __builtin_amdgcn_permlane32_swap(fasu(mx), fasu(mx), false, false);
      mx = fmaxf(uasf(pr_[0]), uasf(pr_[1]));
    }
    if (!__all(mx <= m_run + 8.f)) {
      float mn = fmaxf(m_run, mx);
      float alpha = __expf(m_run - mn);
      l_run *= alpha;
#pragma unroll
      for (int i = 0; i < 16; ++i) {
        o0[i] *= alpha;
        o1[i] *= alpha;
      }
      m_run = mn;
    }
#pragma unroll
    for (int i = 0; i < 16; ++i) {
      SA0[i] = __expf(SA0[i] - m_run);
      SA1[i] = __expf(SA1[i] - m_run);
      SB0[i] = __expf(SB0[i] - m_run);
      SB1[i] = __expf(SB1[i] - m_run);
    }
    float r0 = 0.f, r1 = 0.f, r2 = 0.f, r3 = 0.f;
#pragma unroll
    for (int i = 0; i < 16; ++i) {
      r0 += SA0[i];
      r1 += SA1[i];
      r2 += SB0[i];
      r3 += SB1[i];
    }
    float rs = (r0 + r1) + (r2 + r3);
    {
      auto pr_ = __builtin_amdgcn_permlane32_swap(fasu(rs), fasu(rs), false, false);
      rs = uasf(pr_[0]) + uasf(pr_[1]);
    }
    l_run = l_run + rs;

    // 5. P -> PV B-frags in-register
    bf16x8 pA0, pA1, pA2, pA3, pB0, pB1, pB2, pB3;
    PACK2(SA0, pA0, pA1)
    PACK2(SA1, pA2, pA3)
    PACK2(SB0, pB0, pB1)
    PACK2(SB1, pB2, pB3)

    // 6. O^T += V^T P^T over the 128-key pair
    __builtin_amdgcn_s_setprio(1);
    {
      bf16x8 vf;
      FRAGV(vf, 0, 0 + hi)   o0 = mfma32(vf, pA0, o0);
      FRAGV(vf, 0, 2 + hi)   o0 = mfma32(vf, pA1, o0);
      FRAGV(vf, 0, 4 + hi)   o0 = mfma32(vf, pA2, o0);
      FRAGV(vf, 0, 6 + hi)   o0 = mfma32(vf, pA3, o0);
      FRAGV(vf, 0, 8 + hi)   o0 = mfma32(vf, pB0, o0);
      FRAGV(vf, 0, 10 + hi)  o0 = mfma32(vf, pB1, o0);
      FRAGV(vf, 0, 12 + hi)  o0 = mfma32(vf, pB2, o0);
      FRAGV(vf, 0, 14 + hi)  o0 = mfma32(vf, pB3, o0);
      FRAGV(vf, 32, 0 + hi)  o1 = mfma32(vf, pA0, o1);
      FRAGV(vf, 32, 2 + hi)  o1 = mfma32(vf, pA1, o1);
      FRAGV(vf, 32, 4 + hi)  o1 = mfma32(vf, pA2, o1);
      FRAGV(vf, 32, 6 + hi)  o1 = mfma32(vf, pA3, o1);
      FRAGV(vf, 32, 8 + hi)  o1 = mfma32(vf, pB0, o1);
      FRAGV(vf, 32, 10 + hi) o1 = mfma32(vf, pB1, o1);
      FRAGV(vf, 32, 12 + hi) o1 = mfma32(vf, pB2, o1);
      FRAGV(vf, 32, 14 + hi) o1 = mfma32(vf, pB3, o1);
    }
    __builtin_amdgcn_s_setprio(0);

    // 7. all waves done reading K/V pair p -> stage pair p+1
    asm volatile("s_waitcnt lgkmcnt(0)" ::: "memory");
    __builtin_amdgcn_s_barrier();
    if (p + 1 < NP) {
      const size_t jn = (size_t)(p + 1) * 128;
      STAGE_KV(jn)
    }
  }
#undef STAGE_KV
#undef SBI
#undef STAGE_BIAS
#undef LDBIAS
#undef FRAGK
#undef FRAGV
#undef PACK2

  // epilogue: O[q][d] = O^T / l
  float inv = 1.f / l_run;
  unsigned short* orow =
      Oatt + (size_t)(b * N_ + qbase + l31) * 1024 + h * 64 + hi * 4;
#pragma unroll
  for (int g = 0; g < 4; ++g) {
    u32x2 pk0;
    pk0[0] = cvt_pk_bf16(o0[g * 4 + 0] * inv, o0[g * 4 + 1] * inv);
    pk0[1] = cvt_pk_bf16(o0[g * 4 + 2] * inv, o0[g * 4 + 3] * inv);
    *reinterpret_cast<u32x2*>(orow + g * 8) = pk0;
    u32x2 pk1;
    pk1[0] = cvt_pk_bf16(o1[g * 4 + 0] * inv, o1[g * 4 + 1] * inv);
    pk1[1] = cvt_pk_bf16(o1[g * 4 + 2] * inv, o1[g * 4 + 3] * inv);
    *reinterpret_cast<u32x2*>(orow + 32 + g * 8) = pk1;
  }
}

extern "C" void kernel_launch(void* const* d_in, const int* in_sizes, int n_in, void* d_out,
                              int out_size, void* d_ws, size_t ws_size, hipStream_t stream) {
  const float* x = (const float*)d_in[0];
  const float* bias = (const float*)d_in[1];
  const float* g = (const float*)d_in[2];
  const float* wq = (const float*)d_in[3];
  const float* wkv = (const float*)d_in[4];
  const float* wout = (const float*)d_in[5];
  float* out = (float*)d_out;

  float* ps = (float*)d_ws;
  float* pss = ps + 16 * B_ * DIM_;
  float* meanA = pss + 16 * B_ * DIM_;
  float* sclA = meanA + B_ * DIM_;
  unsigned short* xn = (unsigned short*)(sclA + B_ * DIM_);
  unsigned short* Wqkv = xn + (size_t)4096 * 1024;
  unsigned short* WoutB = Wqkv + (size_t)3072 * 1024;
  unsigned short* qkvb = WoutB + (size_t)1024 * 1024;
  unsigned short* Vt = qkvb + (size_t)4096 * 3072;
  unsigned short* Oatt = xn;  // alias: xn dead after QKV GEMM

  pre_fused<<<dim3(2176), 256, 0, stream>>>(x, ps, pss, wq, wkv, wout, Wqkv, WoutB);
  ln_fin<<<dim3((B_ * DIM_) / 256), 256, 0, stream>>>(ps, pss, g, meanA, sclA);
  ln_apply<<<dim3((B_ * N_ * DIM_) / 2048), 256, 0, stream>>>(x, meanA, sclA, xn);
  gemm_bt<false><<<dim3(3072 / 128, 4096 / 128), 256, 0, stream>>>(xn, Wqkv, qkvb, DIM_, 3072,
                                                                   Vt);
  flash_attn<<<dim3(256), 512, 0, stream>>>(qkvb, bias, Vt, Oatt);
  gemm_bt<true><<<dim3(1024 / 128, 4096 / 128), 256, 0, stream>>>(Oatt, WoutB, out, DIM_, 1024,
                                                                  nullptr);
}